// Round 1
// baseline (5133.621 us; speedup 1.0000x reference)
//
#include <hip/hip_runtime.h>

#define N_NODES   50000
#define N_EDGES   600000
#define F         128
#define N_GRAPHS  512

// ---------------------------------------------------------------------------
// deg[dst] += 1 for each edge
__global__ void deg_kernel(const int* __restrict__ dst, float* __restrict__ deg) {
    int e = blockIdx.x * blockDim.x + threadIdx.x;
    if (e < N_EDGES) atomicAdd(&deg[dst[e]], 1.0f);
}

// cnt[batch[i]] += 1 for each node
__global__ void cnt_kernel(const int* __restrict__ batch, float* __restrict__ cnt) {
    int i = blockIdx.x * blockDim.x + threadIdx.x;
    if (i < N_NODES) atomicAdd(&cnt[batch[i]], 1.0f);
}

// buf[i] = 1 / max(buf[i], 1)
__global__ void inv_kernel(float* __restrict__ buf, int n) {
    int i = blockIdx.x * blockDim.x + threadIdx.x;
    if (i < n) buf[i] = 1.0f / fmaxf(buf[i], 1.0f);
}

// msg[dst] += h[src], 32 threads per edge, float4 loads
__global__ void scatter_kernel(const int* __restrict__ src, const int* __restrict__ dst,
                               const float* __restrict__ h, float* __restrict__ msg) {
    long long idx = (long long)blockIdx.x * blockDim.x + threadIdx.x;
    int e  = (int)(idx >> 5);
    int f4 = (int)(idx & 31);
    if (e < N_EDGES) {
        int s = src[e];
        int d = dst[e];
        float4 v = ((const float4*)(h + (size_t)s * F))[f4];
        float* mp = msg + (size_t)d * F + (size_t)f4 * 4;
        atomicAdd(mp + 0, v.x);
        atomicAdd(mp + 1, v.y);
        atomicAdd(mp + 2, v.z);
        atomicAdd(mp + 3, v.w);
    }
}

// h_out[i,j] = relu( (msg[i,:]*inv_deg[i]) @ Wl[:,j] + h_in[i,:] @ Wr[:,j] + b[j] )
// block = 256 threads = 2 rows x 128 cols. h_out may alias msg (rows are staged
// into LDS before any write, and each block only writes the rows it staged).
__global__ __launch_bounds__(256) void sage_gemm(
    const float* __restrict__ msg, const float* __restrict__ inv_deg,
    const float* __restrict__ h_in,
    const float* __restrict__ Wl, const float* __restrict__ Wr,
    const float* __restrict__ b,
    float* __restrict__ h_out)
{
    __shared__ float la[2][F];
    __shared__ float lh[2][F];
    int r   = threadIdx.x >> 7;      // 0..1
    int j   = threadIdx.x & 127;     // 0..127
    int row = blockIdx.x * 2 + r;
    bool valid = (row < N_NODES);
    if (valid) {
        float s = inv_deg[row];
        la[r][j] = msg[(size_t)row * F + j] * s;
        lh[r][j] = h_in[(size_t)row * F + j];
    }
    __syncthreads();
    if (!valid) return;
    float acc = b[j];
    #pragma unroll 8
    for (int k = 0; k < F; ++k) {
        acc += la[r][k] * Wl[k * F + j];
        acc += lh[r][k] * Wr[k * F + j];
    }
    h_out[(size_t)row * F + j] = fmaxf(acc, 0.0f);
}

// pooled[batch[i]] += h[i], 32 threads per node, float4 loads
__global__ void pool_kernel(const int* __restrict__ batch, const float* __restrict__ h,
                            float* __restrict__ pooled) {
    long long idx = (long long)blockIdx.x * blockDim.x + threadIdx.x;
    int i  = (int)(idx >> 5);
    int f4 = (int)(idx & 31);
    if (i < N_NODES) {
        int g = batch[i];
        float4 v = ((const float4*)(h + (size_t)i * F))[f4];
        float* p = pooled + (size_t)g * F + (size_t)f4 * 4;
        atomicAdd(p + 0, v.x);
        atomicAdd(p + 1, v.y);
        atomicAdd(p + 2, v.z);
        atomicAdd(p + 3, v.w);
    }
}

// out[g,:] = ((pooled[g,:]*inv_cnt[g]) @ Wf1 + bf1) @ Wf2 + bf2
__global__ __launch_bounds__(128) void head_kernel(
    const float* __restrict__ pooled, const float* __restrict__ inv_cnt,
    const float* __restrict__ Wf1, const float* __restrict__ bf1,
    const float* __restrict__ Wf2, const float* __restrict__ bf2,
    float* __restrict__ out)
{
    __shared__ float p[F];
    __shared__ float emb[F];
    int g = blockIdx.x;
    int j = threadIdx.x;          // 0..127
    p[j] = pooled[(size_t)g * F + j] * inv_cnt[g];
    __syncthreads();
    float acc = bf1[j];
    #pragma unroll 8
    for (int k = 0; k < F; ++k) acc += p[k] * Wf1[k * F + j];
    emb[j] = acc;
    __syncthreads();
    if (j < 2) {
        float o = bf2[j];
        for (int k = 0; k < F; ++k) o += emb[k] * Wf2[k * 2 + j];
        out[(size_t)g * 2 + j] = o;
    }
}

extern "C" void kernel_launch(void* const* d_in, const int* in_sizes, int n_in,
                              void* d_out, int out_size, void* d_ws, size_t ws_size,
                              hipStream_t stream) {
    const float* x     = (const float*)d_in[0];
    const int*   ei    = (const int*)d_in[1];
    const int*   src   = ei;               // edge_index[0]
    const int*   dst   = ei + N_EDGES;     // edge_index[1]
    const int*   batch = (const int*)d_in[2];
    // d_in[3] = num_graphs (compile-time constant 512)
    const float* Wl[4] = {(const float*)d_in[4],  (const float*)d_in[7],
                          (const float*)d_in[10], (const float*)d_in[13]};
    const float* Wr[4] = {(const float*)d_in[5],  (const float*)d_in[8],
                          (const float*)d_in[11], (const float*)d_in[14]};
    const float* bb[4] = {(const float*)d_in[6],  (const float*)d_in[9],
                          (const float*)d_in[12], (const float*)d_in[15]};
    const float* Wf1 = (const float*)d_in[16];
    const float* bf1 = (const float*)d_in[17];
    const float* Wf2 = (const float*)d_in[18];
    const float* bf2 = (const float*)d_in[19];
    float* out = (float*)d_out;

    // workspace layout (floats)
    float* ws = (float*)d_ws;
    const size_t HSZ = (size_t)N_NODES * F;            // 6.4M floats
    float* B0     = ws;                                 // h / msg ping
    float* B1     = B0 + HSZ;                           // h / msg pong
    float* deg    = B1 + HSZ;                           // N_NODES (becomes inv_deg)
    float* cnt    = deg + N_NODES;                      // N_GRAPHS (becomes inv_cnt)
    float* pooled = cnt + N_GRAPHS;                     // N_GRAPHS*F

    hipMemsetAsync(deg,    0, N_NODES  * sizeof(float), stream);
    hipMemsetAsync(cnt,    0, N_GRAPHS * sizeof(float), stream);
    hipMemsetAsync(pooled, 0, (size_t)N_GRAPHS * F * sizeof(float), stream);

    deg_kernel<<<(N_EDGES + 255) / 256, 256, 0, stream>>>(dst, deg);
    cnt_kernel<<<(N_NODES + 255) / 256, 256, 0, stream>>>(batch, cnt);
    inv_kernel<<<(N_NODES + 255) / 256, 256, 0, stream>>>(deg, N_NODES);
    inv_kernel<<<(N_GRAPHS + 255) / 256, 256, 0, stream>>>(cnt, N_GRAPHS);

    const int scat_blocks = (N_EDGES * 32 + 255) / 256;   // 75000
    const int gemm_blocks = (N_NODES + 1) / 2;            // 25000

    const float* hin = x;
    float* buf[2] = {B0, B1};
    for (int l = 0; l < 4; ++l) {
        float* tgt = buf[l & 1];
        hipMemsetAsync(tgt, 0, HSZ * sizeof(float), stream);
        scatter_kernel<<<scat_blocks, 256, 0, stream>>>(src, dst, hin, tgt);
        // in-place: gemm reads tgt (msg) + hin, writes tgt (h_out)
        sage_gemm<<<gemm_blocks, 256, 0, stream>>>(tgt, deg, hin, Wl[l], Wr[l], bb[l], tgt);
        hin = tgt;
    }

    const int pool_blocks = (N_NODES * 32 + 255) / 256;
    pool_kernel<<<pool_blocks, 256, 0, stream>>>(batch, hin, pooled);
    head_kernel<<<N_GRAPHS, 128, 0, stream>>>(pooled, cnt, Wf1, bf1, Wf2, bf2, out);
}

// Round 2
// 1180.454 us; speedup vs baseline: 4.3489x; 4.3489x over previous
//
#include <hip/hip_runtime.h>

#define N_NODES   50000
#define N_EDGES   600000
#define F         128
#define N_GRAPHS  512
#define ROWS      8

// ---------------------------------------------------------------------------
// integer degree histogram: deg[dst]++
__global__ void deg_int_kernel(const int* __restrict__ dst, int* __restrict__ deg) {
    int e = blockIdx.x * blockDim.x + threadIdx.x;
    if (e < N_EDGES) atomicAdd(&deg[dst[e]], 1);
}

// cnt[batch[i]] += 1
__global__ void cnt_kernel(const int* __restrict__ batch, float* __restrict__ cnt) {
    int i = blockIdx.x * blockDim.x + threadIdx.x;
    if (i < N_NODES) atomicAdd(&cnt[batch[i]], 1.0f);
}

// buf[i] = 1 / max(buf[i], 1)
__global__ void inv_kernel(float* __restrict__ buf, int n) {
    int i = blockIdx.x * blockDim.x + threadIdx.x;
    if (i < n) buf[i] = 1.0f / fmaxf(buf[i], 1.0f);
}

// single-block exclusive scan of deg -> row_start, cursor; inv_deg as float
__global__ __launch_bounds__(1024) void scan_kernel(
    const int* __restrict__ deg, int* __restrict__ row_start,
    int* __restrict__ cursor, float* __restrict__ inv_deg)
{
    __shared__ int part[1024];
    int t = threadIdx.x;
    const int CH = (N_NODES + 1023) / 1024;  // 49
    int begin = t * CH;
    int end   = begin + CH; if (end > N_NODES) end = N_NODES;
    if (begin > N_NODES) begin = N_NODES;
    int s = 0;
    for (int i = begin; i < end; ++i) s += deg[i];
    part[t] = s;
    __syncthreads();
    // Hillis-Steele inclusive scan
    for (int off = 1; off < 1024; off <<= 1) {
        int v   = part[t];
        int add = (t >= off) ? part[t - off] : 0;
        __syncthreads();
        part[t] = v + add;
        __syncthreads();
    }
    int run = (t == 0) ? 0 : part[t - 1];   // exclusive prefix
    for (int i = begin; i < end; ++i) {
        int d = deg[i];
        row_start[i] = run;
        cursor[i]    = run;
        inv_deg[i]   = 1.0f / fmaxf((float)d, 1.0f);
        run += d;
    }
    if (t == 1023) row_start[N_NODES] = run;  // == total (last chunks empty)
}

// CSR fill: eidx[cursor[dst[e]]++] = src[e]
__global__ void fill_kernel(const int* __restrict__ src, const int* __restrict__ dst,
                            int* __restrict__ cursor, int* __restrict__ eidx) {
    int e = blockIdx.x * blockDim.x + threadIdx.x;
    if (e < N_EDGES) {
        int p = atomicAdd(&cursor[dst[e]], 1);
        eidx[p] = src[e];
    }
}

// Fused layer: gather-mean over in-neighbors + dual GEMM + bias + relu.
// block = 256 threads = 2 groups x 128 cols; ROWS=8 rows/block (4 per group).
__global__ __launch_bounds__(256) void layer_kernel(
    const float* __restrict__ h_in, const int* __restrict__ row_start,
    const int* __restrict__ eidx, const float* __restrict__ inv_deg,
    const float* __restrict__ Wl, const float* __restrict__ Wr,
    const float* __restrict__ b, float* __restrict__ h_out)
{
    __shared__ float la[ROWS][F];
    __shared__ float lh[ROWS][F];
    const int j  = threadIdx.x & 127;   // col
    const int g  = threadIdx.x >> 7;    // 0..1
    const int base = blockIdx.x * ROWS;

    // stage: group g handles rows g*4 .. g*4+3
    for (int rr = 0; rr < 4; ++rr) {
        int r   = g * 4 + rr;
        int row = base + r;
        if (row < N_NODES) {
            int s0 = row_start[row], s1 = row_start[row + 1];
            float acc = 0.0f;
            for (int e = s0; e < s1; ++e)
                acc += h_in[(size_t)eidx[e] * F + j];
            la[r][j] = acc * inv_deg[row];
            lh[r][j] = h_in[(size_t)row * F + j];
        } else {
            la[r][j] = 0.0f;
            lh[r][j] = 0.0f;
        }
    }
    __syncthreads();

    const int r0 = g * 4;
    float bj = b[j];
    float acc0 = bj, acc1 = bj, acc2 = bj, acc3 = bj;
    #pragma unroll 4
    for (int k = 0; k < F; k += 4) {
        float4 a0 = *(const float4*)&la[r0 + 0][k];
        float4 a1 = *(const float4*)&la[r0 + 1][k];
        float4 a2 = *(const float4*)&la[r0 + 2][k];
        float4 a3 = *(const float4*)&la[r0 + 3][k];
        float4 h0 = *(const float4*)&lh[r0 + 0][k];
        float4 h1 = *(const float4*)&lh[r0 + 1][k];
        float4 h2 = *(const float4*)&lh[r0 + 2][k];
        float4 h3 = *(const float4*)&lh[r0 + 3][k];
        #pragma unroll
        for (int kk = 0; kk < 4; ++kk) {
            float wl = Wl[(k + kk) * F + j];
            float wr = Wr[(k + kk) * F + j];
            const float* ap0 = (const float*)&a0; const float* hp0 = (const float*)&h0;
            const float* ap1 = (const float*)&a1; const float* hp1 = (const float*)&h1;
            const float* ap2 = (const float*)&a2; const float* hp2 = (const float*)&h2;
            const float* ap3 = (const float*)&a3; const float* hp3 = (const float*)&h3;
            acc0 += ap0[kk] * wl + hp0[kk] * wr;
            acc1 += ap1[kk] * wl + hp1[kk] * wr;
            acc2 += ap2[kk] * wl + hp2[kk] * wr;
            acc3 += ap3[kk] * wl + hp3[kk] * wr;
        }
    }
    int row = base + r0;
    if (row + 0 < N_NODES) h_out[(size_t)(row + 0) * F + j] = fmaxf(acc0, 0.0f);
    if (row + 1 < N_NODES) h_out[(size_t)(row + 1) * F + j] = fmaxf(acc1, 0.0f);
    if (row + 2 < N_NODES) h_out[(size_t)(row + 2) * F + j] = fmaxf(acc2, 0.0f);
    if (row + 3 < N_NODES) h_out[(size_t)(row + 3) * F + j] = fmaxf(acc3, 0.0f);
}

// pooled[batch[i]] += h[i], 32 threads per node, float4 loads
__global__ void pool_kernel(const int* __restrict__ batch, const float* __restrict__ h,
                            float* __restrict__ pooled) {
    long long idx = (long long)blockIdx.x * blockDim.x + threadIdx.x;
    int i  = (int)(idx >> 5);
    int f4 = (int)(idx & 31);
    if (i < N_NODES) {
        int g = batch[i];
        float4 v = ((const float4*)(h + (size_t)i * F))[f4];
        float* p = pooled + (size_t)g * F + (size_t)f4 * 4;
        atomicAdd(p + 0, v.x);
        atomicAdd(p + 1, v.y);
        atomicAdd(p + 2, v.z);
        atomicAdd(p + 3, v.w);
    }
}

// out[g,:] = ((pooled[g,:]*inv_cnt[g]) @ Wf1 + bf1) @ Wf2 + bf2
__global__ __launch_bounds__(128) void head_kernel(
    const float* __restrict__ pooled, const float* __restrict__ inv_cnt,
    const float* __restrict__ Wf1, const float* __restrict__ bf1,
    const float* __restrict__ Wf2, const float* __restrict__ bf2,
    float* __restrict__ out)
{
    __shared__ float p[F];
    __shared__ float emb[F];
    int g = blockIdx.x;
    int j = threadIdx.x;
    p[j] = pooled[(size_t)g * F + j] * inv_cnt[g];
    __syncthreads();
    float acc = bf1[j];
    #pragma unroll 8
    for (int k = 0; k < F; ++k) acc += p[k] * Wf1[k * F + j];
    emb[j] = acc;
    __syncthreads();
    if (j < 2) {
        float o = bf2[j];
        for (int k = 0; k < F; ++k) o += emb[k] * Wf2[k * 2 + j];
        out[(size_t)g * 2 + j] = o;
    }
}

extern "C" void kernel_launch(void* const* d_in, const int* in_sizes, int n_in,
                              void* d_out, int out_size, void* d_ws, size_t ws_size,
                              hipStream_t stream) {
    const float* x     = (const float*)d_in[0];
    const int*   ei    = (const int*)d_in[1];
    const int*   src   = ei;               // edge_index[0]
    const int*   dst   = ei + N_EDGES;     // edge_index[1]
    const int*   batch = (const int*)d_in[2];
    const float* Wl[4] = {(const float*)d_in[4],  (const float*)d_in[7],
                          (const float*)d_in[10], (const float*)d_in[13]};
    const float* Wr[4] = {(const float*)d_in[5],  (const float*)d_in[8],
                          (const float*)d_in[11], (const float*)d_in[14]};
    const float* bb[4] = {(const float*)d_in[6],  (const float*)d_in[9],
                          (const float*)d_in[12], (const float*)d_in[15]};
    const float* Wf1 = (const float*)d_in[16];
    const float* bf1 = (const float*)d_in[17];
    const float* Wf2 = (const float*)d_in[18];
    const float* bf2 = (const float*)d_in[19];
    float* out = (float*)d_out;

    // workspace layout
    float* ws = (float*)d_ws;
    const size_t HSZ = (size_t)N_NODES * F;            // 6.4M floats
    float* B0      = ws;
    float* B1      = B0 + HSZ;
    float* pooled  = B1 + HSZ;                          // N_GRAPHS*F
    float* inv_deg = pooled + (size_t)N_GRAPHS * F;     // N_NODES
    float* cnt     = inv_deg + N_NODES;                 // N_GRAPHS
    int*   ibase   = (int*)(cnt + N_GRAPHS);
    int*   row_start = ibase;                           // N_NODES+1
    int*   cursor    = row_start + N_NODES + 1;         // N_NODES
    int*   eidx      = cursor + N_NODES;                // N_EDGES
    int*   deg_i     = eidx + N_EDGES;                  // N_NODES

    hipMemsetAsync(deg_i,  0, N_NODES  * sizeof(int),   stream);
    hipMemsetAsync(cnt,    0, N_GRAPHS * sizeof(float), stream);
    hipMemsetAsync(pooled, 0, (size_t)N_GRAPHS * F * sizeof(float), stream);

    // CSR build (once per call; shared by all 4 layers)
    deg_int_kernel<<<(N_EDGES + 255) / 256, 256, 0, stream>>>(dst, deg_i);
    scan_kernel<<<1, 1024, 0, stream>>>(deg_i, row_start, cursor, inv_deg);
    fill_kernel<<<(N_EDGES + 255) / 256, 256, 0, stream>>>(src, dst, cursor, eidx);

    cnt_kernel<<<(N_NODES + 255) / 256, 256, 0, stream>>>(batch, cnt);
    inv_kernel<<<(N_GRAPHS + 255) / 256, 256, 0, stream>>>(cnt, N_GRAPHS);

    const int layer_blocks = (N_NODES + ROWS - 1) / ROWS;   // 6250
    const float* hin = x;
    float* buf[2] = {B0, B1};
    for (int l = 0; l < 4; ++l) {
        float* tgt = buf[l & 1];
        layer_kernel<<<layer_blocks, 256, 0, stream>>>(
            hin, row_start, eidx, inv_deg, Wl[l], Wr[l], bb[l], tgt);
        hin = tgt;
    }

    const int pool_blocks = (N_NODES * 32 + 255) / 256;
    pool_kernel<<<pool_blocks, 256, 0, stream>>>(batch, hin, pooled);
    head_kernel<<<N_GRAPHS, 128, 0, stream>>>(pooled, cnt, Wf1, bf1, Wf2, bf2, out);
}

// Round 4
// 896.844 us; speedup vs baseline: 5.7241x; 1.3162x over previous
//
#include <hip/hip_runtime.h>

#define N_NODES   50000
#define N_EDGES   600000
#define F         128
#define N_GRAPHS  512
#define MROWS     32          // rows per block in layer kernel
#define ASTRIDE   264         // LDS row stride in shorts (16B-aligned, breaks pow2)

typedef short  short8 __attribute__((ext_vector_type(8)));
typedef short  short4_t __attribute__((ext_vector_type(4)));
typedef float  f32x4  __attribute__((ext_vector_type(4)));

__device__ __forceinline__ void split_bf16(float v, short& hi, short& lo) {
    unsigned u  = __float_as_uint(v);
    unsigned hb = u & 0xFFFF0000u;
    hi = (short)(u >> 16);
    float rem = v - __uint_as_float(hb);
    lo = (short)(__float_as_uint(rem) >> 16);
}

__device__ __forceinline__ void split4(float x, float y, float z, float w,
                                       short4_t& hi, short4_t& lo) {
    short h, l;
    split_bf16(x, h, l); hi[0] = h; lo[0] = l;
    split_bf16(y, h, l); hi[1] = h; lo[1] = l;
    split_bf16(z, h, l); hi[2] = h; lo[2] = l;
    split_bf16(w, h, l); hi[3] = h; lo[3] = l;
}

// ---------------------------------------------------------------------------
__global__ void deg_int_kernel(const int* __restrict__ dst, int* __restrict__ deg) {
    int e = blockIdx.x * blockDim.x + threadIdx.x;
    if (e < N_EDGES) atomicAdd(&deg[dst[e]], 1);
}

__global__ void cnt_kernel(const int* __restrict__ batch, float* __restrict__ cnt) {
    int i = blockIdx.x * blockDim.x + threadIdx.x;
    if (i < N_NODES) atomicAdd(&cnt[batch[i]], 1.0f);
}

__global__ void inv_kernel(float* __restrict__ buf, int n) {
    int i = blockIdx.x * blockDim.x + threadIdx.x;
    if (i < n) buf[i] = 1.0f / fmaxf(buf[i], 1.0f);
}

__global__ __launch_bounds__(1024) void scan_kernel(
    const int* __restrict__ deg, int* __restrict__ row_start,
    int* __restrict__ cursor, float* __restrict__ inv_deg)
{
    __shared__ int part[1024];
    int t = threadIdx.x;
    const int CH = (N_NODES + 1023) / 1024;  // 49
    int begin = t * CH;
    int end   = begin + CH; if (end > N_NODES) end = N_NODES;
    if (begin > N_NODES) begin = N_NODES;
    int s = 0;
    for (int i = begin; i < end; ++i) s += deg[i];
    part[t] = s;
    __syncthreads();
    for (int off = 1; off < 1024; off <<= 1) {
        int v   = part[t];
        int add = (t >= off) ? part[t - off] : 0;
        __syncthreads();
        part[t] = v + add;
        __syncthreads();
    }
    int run = (t == 0) ? 0 : part[t - 1];
    for (int i = begin; i < end; ++i) {
        int d = deg[i];
        row_start[i] = run;
        cursor[i]    = run;
        inv_deg[i]   = 1.0f / fmaxf((float)d, 1.0f);
        run += d;
    }
    if (t == 1023) row_start[N_NODES] = run;
}

__global__ void fill_kernel(const int* __restrict__ src, const int* __restrict__ dst,
                            int* __restrict__ cursor, int* __restrict__ eidx) {
    int e = blockIdx.x * blockDim.x + threadIdx.x;
    if (e < N_EDGES) {
        int p = atomicAdd(&cursor[dst[e]], 1);
        eidx[p] = src[e];
    }
}

// W pre-transpose + split: Wt[n][k] (k<128 -> Wl[k][n], else Wr[k-128][n]), bf16 hi/lo
__global__ __launch_bounds__(256) void wsplit_kernel(
    const float* __restrict__ Wl, const float* __restrict__ Wr,
    short* __restrict__ hi, short* __restrict__ lo)
{
    int t = blockIdx.x * blockDim.x + threadIdx.x;   // t = n*256 + k
    int n = t >> 8, k = t & 255;
    float w = (k < F) ? Wl[k * F + n] : Wr[(k - F) * F + n];
    short h, l;
    split_bf16(w, h, l);
    hi[t] = h; lo[t] = l;
}

// ---------------------------------------------------------------------------
// Fused layer: f32 gather-mean -> split-bf16 MFMA dual-GEMM -> bias+relu.
// block = 256 threads (4 waves), 32 rows. A = [agg | self] : [32 x 256].
__global__ __launch_bounds__(256) void layer_kernel(
    const float* __restrict__ h_in, const int* __restrict__ row_start,
    const int* __restrict__ eidx, const float* __restrict__ inv_deg,
    const short* __restrict__ wt_hi, const short* __restrict__ wt_lo,
    const float* __restrict__ b, float* __restrict__ h_out)
{
    __shared__ short Ahi[MROWS][ASTRIDE];
    __shared__ short Alo[MROWS][ASTRIDE];

    const int t    = threadIdx.x;
    const int base = blockIdx.x * MROWS;

    // ---- gather phase: c4 = float4 col group, rr = row slot ----
    {
        const int c4 = t & 31;
        const int rr = t >> 5;   // 0..7
        for (int p = 0; p < 4; ++p) {
            int rl  = p * 8 + rr;
            int row = base + rl;
            float ax = 0.f, ay = 0.f, az = 0.f, aw = 0.f;
            float sx = 0.f, sy = 0.f, sz = 0.f, sw = 0.f;
            if (row < N_NODES) {
                int s0 = row_start[row], s1 = row_start[row + 1];
                for (int e = s0; e < s1; ++e) {
                    int idx = eidx[e];
                    float4 v = ((const float4*)(h_in + (size_t)idx * F))[c4];
                    ax += v.x; ay += v.y; az += v.z; aw += v.w;
                }
                float sc = inv_deg[row];
                ax *= sc; ay *= sc; az *= sc; aw *= sc;
                float4 s = ((const float4*)(h_in + (size_t)row * F))[c4];
                sx = s.x; sy = s.y; sz = s.z; sw = s.w;
            }
            short4_t h4, l4;
            split4(ax, ay, az, aw, h4, l4);
            *(short4_t*)&Ahi[rl][c4 * 4] = h4;
            *(short4_t*)&Alo[rl][c4 * 4] = l4;
            split4(sx, sy, sz, sw, h4, l4);
            *(short4_t*)&Ahi[rl][F + c4 * 4] = h4;
            *(short4_t*)&Alo[rl][F + c4 * 4] = l4;
        }
    }
    __syncthreads();

    // ---- MFMA phase: wave w owns cols [w*32, w*32+32) ----
    const int w    = t >> 6;
    const int lane = t & 63;
    const int m    = lane & 15;
    const int quad = lane >> 4;

    f32x4 acc00 = {0,0,0,0}, acc01 = {0,0,0,0};
    f32x4 acc10 = {0,0,0,0}, acc11 = {0,0,0,0};

    const int n0 = w * 32 + m;        // nt=0 column for this lane
    const int n1 = n0 + 16;           // nt=1 column

    #pragma unroll
    for (int ks = 0; ks < 8; ++ks) {
        const int ko = ks * 32 + quad * 8;
        short8 ah0 = *(const short8*)&Ahi[m][ko];
        short8 ah1 = *(const short8*)&Ahi[16 + m][ko];
        short8 al0 = *(const short8*)&Alo[m][ko];
        short8 al1 = *(const short8*)&Alo[16 + m][ko];
        short8 bh0 = *(const short8*)&wt_hi[(size_t)n0 * 256 + ko];
        short8 bh1 = *(const short8*)&wt_hi[(size_t)n1 * 256 + ko];
        short8 bl0 = *(const short8*)&wt_lo[(size_t)n0 * 256 + ko];
        short8 bl1 = *(const short8*)&wt_lo[(size_t)n1 * 256 + ko];

        acc00 = __builtin_amdgcn_mfma_f32_16x16x32_bf16(ah0, bh0, acc00, 0, 0, 0);
        acc00 = __builtin_amdgcn_mfma_f32_16x16x32_bf16(ah0, bl0, acc00, 0, 0, 0);
        acc00 = __builtin_amdgcn_mfma_f32_16x16x32_bf16(al0, bh0, acc00, 0, 0, 0);

        acc01 = __builtin_amdgcn_mfma_f32_16x16x32_bf16(ah0, bh1, acc01, 0, 0, 0);
        acc01 = __builtin_amdgcn_mfma_f32_16x16x32_bf16(ah0, bl1, acc01, 0, 0, 0);
        acc01 = __builtin_amdgcn_mfma_f32_16x16x32_bf16(al0, bh1, acc01, 0, 0, 0);

        acc10 = __builtin_amdgcn_mfma_f32_16x16x32_bf16(ah1, bh0, acc10, 0, 0, 0);
        acc10 = __builtin_amdgcn_mfma_f32_16x16x32_bf16(ah1, bl0, acc10, 0, 0, 0);
        acc10 = __builtin_amdgcn_mfma_f32_16x16x32_bf16(al1, bh0, acc10, 0, 0, 0);

        acc11 = __builtin_amdgcn_mfma_f32_16x16x32_bf16(ah1, bh1, acc11, 0, 0, 0);
        acc11 = __builtin_amdgcn_mfma_f32_16x16x32_bf16(ah1, bl1, acc11, 0, 0, 0);
        acc11 = __builtin_amdgcn_mfma_f32_16x16x32_bf16(al1, bh1, acc11, 0, 0, 0);
    }

    // ---- epilogue: C/D layout col=lane&15, row=quad*4+reg ----
    float b0 = b[n0];
    float b1 = b[n1];
    #pragma unroll
    for (int reg = 0; reg < 4; ++reg) {
        int r0 = base + quad * 4 + reg;          // mt=0
        int r1 = r0 + 16;                        // mt=1
        if (r0 < N_NODES) {
            h_out[(size_t)r0 * F + n0] = fmaxf(acc00[reg] + b0, 0.0f);
            h_out[(size_t)r0 * F + n1] = fmaxf(acc01[reg] + b1, 0.0f);
        }
        if (r1 < N_NODES) {
            h_out[(size_t)r1 * F + n0] = fmaxf(acc10[reg] + b0, 0.0f);
            h_out[(size_t)r1 * F + n1] = fmaxf(acc11[reg] + b1, 0.0f);
        }
    }
}

// ---------------------------------------------------------------------------
__global__ void pool_kernel(const int* __restrict__ batch, const float* __restrict__ h,
                            float* __restrict__ pooled) {
    long long idx = (long long)blockIdx.x * blockDim.x + threadIdx.x;
    int i  = (int)(idx >> 5);
    int f4 = (int)(idx & 31);
    if (i < N_NODES) {
        int g = batch[i];
        float4 v = ((const float4*)(h + (size_t)i * F))[f4];
        float* p = pooled + (size_t)g * F + (size_t)f4 * 4;
        atomicAdd(p + 0, v.x);
        atomicAdd(p + 1, v.y);
        atomicAdd(p + 2, v.z);
        atomicAdd(p + 3, v.w);
    }
}

__global__ __launch_bounds__(128) void head_kernel(
    const float* __restrict__ pooled, const float* __restrict__ inv_cnt,
    const float* __restrict__ Wf1, const float* __restrict__ bf1,
    const float* __restrict__ Wf2, const float* __restrict__ bf2,
    float* __restrict__ out)
{
    __shared__ float p[F];
    __shared__ float emb[F];
    int g = blockIdx.x;
    int j = threadIdx.x;
    p[j] = pooled[(size_t)g * F + j] * inv_cnt[g];
    __syncthreads();
    float acc = bf1[j];
    #pragma unroll 8
    for (int k = 0; k < F; ++k) acc += p[k] * Wf1[k * F + j];
    emb[j] = acc;
    __syncthreads();
    if (j < 2) {
        float o = bf2[j];
        for (int k = 0; k < F; ++k) o += emb[k] * Wf2[k * 2 + j];
        out[(size_t)g * 2 + j] = o;
    }
}

extern "C" void kernel_launch(void* const* d_in, const int* in_sizes, int n_in,
                              void* d_out, int out_size, void* d_ws, size_t ws_size,
                              hipStream_t stream) {
    const float* x     = (const float*)d_in[0];
    const int*   ei    = (const int*)d_in[1];
    const int*   src   = ei;
    const int*   dst   = ei + N_EDGES;
    const int*   batch = (const int*)d_in[2];
    const float* Wl[4] = {(const float*)d_in[4],  (const float*)d_in[7],
                          (const float*)d_in[10], (const float*)d_in[13]};
    const float* Wr[4] = {(const float*)d_in[5],  (const float*)d_in[8],
                          (const float*)d_in[11], (const float*)d_in[14]};
    const float* bb[4] = {(const float*)d_in[6],  (const float*)d_in[9],
                          (const float*)d_in[12], (const float*)d_in[15]};
    const float* Wf1 = (const float*)d_in[16];
    const float* bf1 = (const float*)d_in[17];
    const float* Wf2 = (const float*)d_in[18];
    const float* bf2 = (const float*)d_in[19];
    float* out = (float*)d_out;

    // workspace layout
    float* ws = (float*)d_ws;
    const size_t HSZ = (size_t)N_NODES * F;
    float* B0      = ws;
    float* B1      = B0 + HSZ;
    float* pooled  = B1 + HSZ;
    float* inv_deg = pooled + (size_t)N_GRAPHS * F;
    float* cnt     = inv_deg + N_NODES;
    int*   row_start = (int*)(cnt + N_GRAPHS);          // N_NODES+1
    int*   cursor    = row_start + N_NODES + 1;         // N_NODES
    int*   eidx      = cursor + N_NODES;                // N_EDGES
    int*   deg_i     = eidx + N_EDGES;                  // N_NODES
    short* wtbase    = (short*)(deg_i + N_NODES);       // 4 layers x 2 x 32768 shorts
    short* Wt_hi[4], *Wt_lo[4];
    for (int l = 0; l < 4; ++l) {
        Wt_hi[l] = wtbase + (size_t)l * 2 * 32768;
        Wt_lo[l] = Wt_hi[l] + 32768;
    }

    (void)hipMemsetAsync(deg_i,  0, N_NODES  * sizeof(int),   stream);
    (void)hipMemsetAsync(cnt,    0, N_GRAPHS * sizeof(float), stream);
    (void)hipMemsetAsync(pooled, 0, (size_t)N_GRAPHS * F * sizeof(float), stream);

    // CSR build
    deg_int_kernel<<<(N_EDGES + 255) / 256, 256, 0, stream>>>(dst, deg_i);
    scan_kernel<<<1, 1024, 0, stream>>>(deg_i, row_start, cursor, inv_deg);
    fill_kernel<<<(N_EDGES + 255) / 256, 256, 0, stream>>>(src, dst, cursor, eidx);

    cnt_kernel<<<(N_NODES + 255) / 256, 256, 0, stream>>>(batch, cnt);
    inv_kernel<<<(N_GRAPHS + 255) / 256, 256, 0, stream>>>(cnt, N_GRAPHS);

    // W transpose+split (once per call)
    for (int l = 0; l < 4; ++l)
        wsplit_kernel<<<128, 256, 0, stream>>>(Wl[l], Wr[l], Wt_hi[l], Wt_lo[l]);

    const int layer_blocks = (N_NODES + MROWS - 1) / MROWS;  // 1563
    const float* hin = x;
    float* buf[2] = {B0, B1};
    for (int l = 0; l < 4; ++l) {
        float* tgt = buf[l & 1];
        layer_kernel<<<layer_blocks, 256, 0, stream>>>(
            hin, row_start, eidx, inv_deg, Wt_hi[l], Wt_lo[l], bb[l], tgt);
        hin = tgt;
    }

    const int pool_blocks = (N_NODES * 32 + 255) / 256;
    pool_kernel<<<pool_blocks, 256, 0, stream>>>(batch, hin, pooled);
    head_kernel<<<N_GRAPHS, 128, 0, stream>>>(pooled, cnt, Wf1, bf1, Wf2, bf2, out);
}

// Round 5
// 553.911 us; speedup vs baseline: 9.2679x; 1.6191x over previous
//
#include <hip/hip_runtime.h>

#define N_NODES   50000
#define N_EDGES   600000
#define F         128
#define N_GRAPHS  512
#define MROWS     32          // rows per block in layer kernel
#define ASTRIDE   264         // LDS row stride in shorts (16B-aligned, breaks pow2)
#define NB_SCAN   196         // ceil(N_NODES/256)

typedef short  short8 __attribute__((ext_vector_type(8)));
typedef short  short4_t __attribute__((ext_vector_type(4)));
typedef float  f32x4  __attribute__((ext_vector_type(4)));

__device__ __forceinline__ void split_bf16(float v, short& hi, short& lo) {
    unsigned u  = __float_as_uint(v);
    unsigned hb = u & 0xFFFF0000u;
    hi = (short)(u >> 16);
    float rem = v - __uint_as_float(hb);
    lo = (short)(__float_as_uint(rem) >> 16);
}

__device__ __forceinline__ void split4(float x, float y, float z, float w,
                                       short4_t& hi, short4_t& lo) {
    short h, l;
    split_bf16(x, h, l); hi[0] = h; lo[0] = l;
    split_bf16(y, h, l); hi[1] = h; lo[1] = l;
    split_bf16(z, h, l); hi[2] = h; lo[2] = l;
    split_bf16(w, h, l); hi[3] = h; lo[3] = l;
}

// ---------------------------------------------------------------------------
__global__ void deg_int_kernel(const int* __restrict__ dst, int* __restrict__ deg) {
    int e = blockIdx.x * blockDim.x + threadIdx.x;
    if (e < N_EDGES) atomicAdd(&deg[dst[e]], 1);
}

__global__ void cnt_kernel(const int* __restrict__ batch, float* __restrict__ cnt) {
    int i = blockIdx.x * blockDim.x + threadIdx.x;
    if (i < N_NODES) atomicAdd(&cnt[batch[i]], 1.0f);
}

__global__ void inv_kernel(float* __restrict__ buf, int n) {
    int i = blockIdx.x * blockDim.x + threadIdx.x;
    if (i < n) buf[i] = 1.0f / fmaxf(buf[i], 1.0f);
}

// ---- parallel scan: phase 1 — per-block sums of deg ----
__global__ __launch_bounds__(256) void bsum_kernel(const int* __restrict__ deg,
                                                   int* __restrict__ bsum) {
    int i = blockIdx.x * 256 + threadIdx.x;
    int v = (i < N_NODES) ? deg[i] : 0;
    #pragma unroll
    for (int off = 32; off > 0; off >>= 1) v += __shfl_down(v, off, 64);
    __shared__ int wsum[4];
    int lane = threadIdx.x & 63, w = threadIdx.x >> 6;
    if (lane == 0) wsum[w] = v;
    __syncthreads();
    if (threadIdx.x == 0) bsum[blockIdx.x] = wsum[0] + wsum[1] + wsum[2] + wsum[3];
}

// ---- phase 2 — single-block exclusive scan of the 196 block sums ----
__global__ __launch_bounds__(256) void bscan_kernel(int* __restrict__ bsum) {
    __shared__ int s[256];
    int t = threadIdx.x;
    int v = (t < NB_SCAN) ? bsum[t] : 0;
    s[t] = v;
    __syncthreads();
    for (int off = 1; off < 256; off <<= 1) {
        int x = s[t];
        int add = (t >= off) ? s[t - off] : 0;
        __syncthreads();
        s[t] = x + add;
        __syncthreads();
    }
    bsum[t] = (t == 0) ? 0 : s[t - 1];   // exclusive
}

// ---- phase 3 — per-block scan + apply ----
__global__ __launch_bounds__(256) void scan_apply_kernel(
    const int* __restrict__ deg, const int* __restrict__ boff,
    int* __restrict__ row_start, int* __restrict__ cursor,
    float* __restrict__ inv_deg)
{
    __shared__ int s[256];
    int b = blockIdx.x, t = threadIdx.x;
    int i = b * 256 + t;
    int d = (i < N_NODES) ? deg[i] : 0;
    s[t] = d;
    __syncthreads();
    for (int off = 1; off < 256; off <<= 1) {
        int x = s[t];
        int add = (t >= off) ? s[t - off] : 0;
        __syncthreads();
        s[t] = x + add;
        __syncthreads();
    }
    int excl = s[t] - d + boff[b];
    if (i < N_NODES) {
        row_start[i] = excl;
        cursor[i]    = excl;
        inv_deg[i]   = 1.0f / fmaxf((float)d, 1.0f);
    }
    if (b == 0 && t == 0) row_start[N_NODES] = N_EDGES;
}

__global__ void fill_kernel(const int* __restrict__ src, const int* __restrict__ dst,
                            int* __restrict__ cursor, int* __restrict__ eidx) {
    int e = blockIdx.x * blockDim.x + threadIdx.x;
    if (e < N_EDGES) {
        int p = atomicAdd(&cursor[dst[e]], 1);
        eidx[p] = src[e];
    }
}

// W pre-transpose + split: Wt[n][k] (k<128 -> Wl[k][n], else Wr[k-128][n]), bf16 hi/lo
__global__ __launch_bounds__(256) void wsplit_kernel(
    const float* __restrict__ Wl, const float* __restrict__ Wr,
    short* __restrict__ hi, short* __restrict__ lo)
{
    int t = blockIdx.x * blockDim.x + threadIdx.x;   // t = n*256 + k
    int n = t >> 8, k = t & 255;
    float w = (k < F) ? Wl[k * F + n] : Wr[(k - F) * F + n];
    short h, l;
    split_bf16(w, h, l);
    hi[t] = h; lo[t] = l;
}

// ---------------------------------------------------------------------------
// Fused layer: f32 gather-mean -> split-bf16 MFMA dual-GEMM -> bias+relu.
// block = 512 threads (8 waves), 32 rows. A = [agg | self] : [32 x 256].
__global__ __launch_bounds__(512) void layer_kernel(
    const float* __restrict__ h_in, const int* __restrict__ row_start,
    const int* __restrict__ eidx, const float* __restrict__ inv_deg,
    const short* __restrict__ wt_hi, const short* __restrict__ wt_lo,
    const float* __restrict__ b, float* __restrict__ h_out)
{
    __shared__ short Ahi[MROWS][ASTRIDE];
    __shared__ short Alo[MROWS][ASTRIDE];

    const int t    = threadIdx.x;
    const int base = blockIdx.x * MROWS;

    // ---- gather phase: 512 threads = 32 float4-col groups x 16 row slots ----
    {
        const int c4 = t & 31;
        const int rr = t >> 5;   // 0..15
        #pragma unroll
        for (int p = 0; p < 2; ++p) {
            int rl  = p * 16 + rr;
            int row = base + rl;
            float ax = 0.f, ay = 0.f, az = 0.f, aw = 0.f;
            float sx = 0.f, sy = 0.f, sz = 0.f, sw = 0.f;
            if (row < N_NODES) {
                int s0 = row_start[row], s1 = row_start[row + 1];
                int e = s0;
                for (; e + 4 <= s1; e += 4) {
                    int i0 = eidx[e + 0], i1 = eidx[e + 1];
                    int i2 = eidx[e + 2], i3 = eidx[e + 3];
                    float4 v0 = ((const float4*)(h_in + (size_t)i0 * F))[c4];
                    float4 v1 = ((const float4*)(h_in + (size_t)i1 * F))[c4];
                    float4 v2 = ((const float4*)(h_in + (size_t)i2 * F))[c4];
                    float4 v3 = ((const float4*)(h_in + (size_t)i3 * F))[c4];
                    ax += (v0.x + v1.x) + (v2.x + v3.x);
                    ay += (v0.y + v1.y) + (v2.y + v3.y);
                    az += (v0.z + v1.z) + (v2.z + v3.z);
                    aw += (v0.w + v1.w) + (v2.w + v3.w);
                }
                for (; e < s1; ++e) {
                    int idx = eidx[e];
                    float4 v = ((const float4*)(h_in + (size_t)idx * F))[c4];
                    ax += v.x; ay += v.y; az += v.z; aw += v.w;
                }
                float sc = inv_deg[row];
                ax *= sc; ay *= sc; az *= sc; aw *= sc;
                float4 s = ((const float4*)(h_in + (size_t)row * F))[c4];
                sx = s.x; sy = s.y; sz = s.z; sw = s.w;
            }
            short4_t h4, l4;
            split4(ax, ay, az, aw, h4, l4);
            *(short4_t*)&Ahi[rl][c4 * 4] = h4;
            *(short4_t*)&Alo[rl][c4 * 4] = l4;
            split4(sx, sy, sz, sw, h4, l4);
            *(short4_t*)&Ahi[rl][F + c4 * 4] = h4;
            *(short4_t*)&Alo[rl][F + c4 * 4] = l4;
        }
    }
    __syncthreads();

    // ---- MFMA phase: wave w owns cols [w*16, w*16+16) ----
    const int w    = t >> 6;         // 0..7
    const int lane = t & 63;
    const int m    = lane & 15;
    const int quad = lane >> 4;
    const int n0   = w * 16 + m;

    f32x4 acc0 = {0,0,0,0};          // rows 0..15
    f32x4 acc1 = {0,0,0,0};          // rows 16..31

    #pragma unroll
    for (int ks = 0; ks < 8; ++ks) {
        const int ko = ks * 32 + quad * 8;
        short8 ah0 = *(const short8*)&Ahi[m][ko];
        short8 ah1 = *(const short8*)&Ahi[16 + m][ko];
        short8 al0 = *(const short8*)&Alo[m][ko];
        short8 al1 = *(const short8*)&Alo[16 + m][ko];
        short8 bh  = *(const short8*)&wt_hi[(size_t)n0 * 256 + ko];
        short8 bl  = *(const short8*)&wt_lo[(size_t)n0 * 256 + ko];

        acc0 = __builtin_amdgcn_mfma_f32_16x16x32_bf16(ah0, bh, acc0, 0, 0, 0);
        acc0 = __builtin_amdgcn_mfma_f32_16x16x32_bf16(ah0, bl, acc0, 0, 0, 0);
        acc0 = __builtin_amdgcn_mfma_f32_16x16x32_bf16(al0, bh, acc0, 0, 0, 0);

        acc1 = __builtin_amdgcn_mfma_f32_16x16x32_bf16(ah1, bh, acc1, 0, 0, 0);
        acc1 = __builtin_amdgcn_mfma_f32_16x16x32_bf16(ah1, bl, acc1, 0, 0, 0);
        acc1 = __builtin_amdgcn_mfma_f32_16x16x32_bf16(al1, bh, acc1, 0, 0, 0);
    }

    // ---- epilogue: C/D layout col=lane&15 (=n0 col), row=quad*4+reg ----
    float bj = b[n0];
    #pragma unroll
    for (int reg = 0; reg < 4; ++reg) {
        int r0 = base + quad * 4 + reg;
        int r1 = r0 + 16;
        if (r0 < N_NODES) h_out[(size_t)r0 * F + n0] = fmaxf(acc0[reg] + bj, 0.0f);
        if (r1 < N_NODES) h_out[(size_t)r1 * F + n0] = fmaxf(acc1[reg] + bj, 0.0f);
    }
}

// ---------------------------------------------------------------------------
// Segmented pool: batch is sorted; each block walks 128 consecutive nodes,
// accumulating per-column until the graph id changes -> few atomics.
__global__ __launch_bounds__(128) void pool_kernel(
    const int* __restrict__ batch, const float* __restrict__ h,
    float* __restrict__ pooled)
{
    int j  = threadIdx.x;            // col
    int n0 = blockIdx.x * 128;
    int g  = batch[n0];
    float acc = 0.0f;
    #pragma unroll 4
    for (int r = 0; r < 128; ++r) {
        int row = n0 + r;
        if (row >= N_NODES) break;
        int gb = batch[row];
        if (gb != g) {
            atomicAdd(&pooled[(size_t)g * F + j], acc);
            acc = 0.0f;
            g = gb;
        }
        acc += h[(size_t)row * F + j];
    }
    atomicAdd(&pooled[(size_t)g * F + j], acc);
}

__global__ __launch_bounds__(128) void head_kernel(
    const float* __restrict__ pooled, const float* __restrict__ inv_cnt,
    const float* __restrict__ Wf1, const float* __restrict__ bf1,
    const float* __restrict__ Wf2, const float* __restrict__ bf2,
    float* __restrict__ out)
{
    __shared__ float p[F];
    __shared__ float emb[F];
    int g = blockIdx.x;
    int j = threadIdx.x;
    p[j] = pooled[(size_t)g * F + j] * inv_cnt[g];
    __syncthreads();
    float acc = bf1[j];
    #pragma unroll 8
    for (int k = 0; k < F; ++k) acc += p[k] * Wf1[k * F + j];
    emb[j] = acc;
    __syncthreads();
    if (j < 2) {
        float o = bf2[j];
        for (int k = 0; k < F; ++k) o += emb[k] * Wf2[k * 2 + j];
        out[(size_t)g * 2 + j] = o;
    }
}

extern "C" void kernel_launch(void* const* d_in, const int* in_sizes, int n_in,
                              void* d_out, int out_size, void* d_ws, size_t ws_size,
                              hipStream_t stream) {
    const float* x     = (const float*)d_in[0];
    const int*   ei    = (const int*)d_in[1];
    const int*   src   = ei;
    const int*   dst   = ei + N_EDGES;
    const int*   batch = (const int*)d_in[2];
    const float* Wl[4] = {(const float*)d_in[4],  (const float*)d_in[7],
                          (const float*)d_in[10], (const float*)d_in[13]};
    const float* Wr[4] = {(const float*)d_in[5],  (const float*)d_in[8],
                          (const float*)d_in[11], (const float*)d_in[14]};
    const float* bb[4] = {(const float*)d_in[6],  (const float*)d_in[9],
                          (const float*)d_in[12], (const float*)d_in[15]};
    const float* Wf1 = (const float*)d_in[16];
    const float* bf1 = (const float*)d_in[17];
    const float* Wf2 = (const float*)d_in[18];
    const float* bf2 = (const float*)d_in[19];
    float* out = (float*)d_out;

    // workspace layout
    float* ws = (float*)d_ws;
    const size_t HSZ = (size_t)N_NODES * F;
    float* B0      = ws;
    float* B1      = B0 + HSZ;
    float* pooled  = B1 + HSZ;
    float* inv_deg = pooled + (size_t)N_GRAPHS * F;
    float* cnt     = inv_deg + N_NODES;
    int*   row_start = (int*)(cnt + N_GRAPHS);          // N_NODES+1
    int*   cursor    = row_start + N_NODES + 1;         // N_NODES
    int*   eidx      = cursor + N_NODES;                // N_EDGES
    int*   deg_i     = eidx + N_EDGES;                  // N_NODES
    int*   bsum      = deg_i + N_NODES;                 // 256
    short* wtbase    = (short*)(bsum + 256);            // 4 layers x 2 x 32768 shorts
    short* Wt_hi[4], *Wt_lo[4];
    for (int l = 0; l < 4; ++l) {
        Wt_hi[l] = wtbase + (size_t)l * 2 * 32768;
        Wt_lo[l] = Wt_hi[l] + 32768;
    }

    (void)hipMemsetAsync(deg_i,  0, N_NODES  * sizeof(int),   stream);
    (void)hipMemsetAsync(cnt,    0, N_GRAPHS * sizeof(float), stream);
    (void)hipMemsetAsync(pooled, 0, (size_t)N_GRAPHS * F * sizeof(float), stream);

    // CSR build
    deg_int_kernel<<<(N_EDGES + 255) / 256, 256, 0, stream>>>(dst, deg_i);
    bsum_kernel<<<NB_SCAN, 256, 0, stream>>>(deg_i, bsum);
    bscan_kernel<<<1, 256, 0, stream>>>(bsum);
    scan_apply_kernel<<<NB_SCAN, 256, 0, stream>>>(deg_i, bsum, row_start, cursor, inv_deg);
    fill_kernel<<<(N_EDGES + 255) / 256, 256, 0, stream>>>(src, dst, cursor, eidx);

    cnt_kernel<<<(N_NODES + 255) / 256, 256, 0, stream>>>(batch, cnt);
    inv_kernel<<<(N_GRAPHS + 255) / 256, 256, 0, stream>>>(cnt, N_GRAPHS);

    // W transpose+split (once per call)
    for (int l = 0; l < 4; ++l)
        wsplit_kernel<<<128, 256, 0, stream>>>(Wl[l], Wr[l], Wt_hi[l], Wt_lo[l]);

    const int layer_blocks = (N_NODES + MROWS - 1) / MROWS;  // 1563
    const float* hin = x;
    float* buf[2] = {B0, B1};
    for (int l = 0; l < 4; ++l) {
        float* tgt = buf[l & 1];
        layer_kernel<<<layer_blocks, 512, 0, stream>>>(
            hin, row_start, eidx, inv_deg, Wt_hi[l], Wt_lo[l], bb[l], tgt);
        hin = tgt;
    }

    const int pool_blocks = (N_NODES + 127) / 128;
    pool_kernel<<<pool_blocks, 128, 0, stream>>>(batch, hin, pooled);
    head_kernel<<<N_GRAPHS, 128, 0, stream>>>(pooled, cnt, Wf1, bf1, Wf2, bf2, out);
}

// Round 6
// 504.348 us; speedup vs baseline: 10.1787x; 1.0983x over previous
//
#include <hip/hip_runtime.h>

#define N_NODES   50000
#define N_EDGES   600000
#define F         128
#define N_GRAPHS  512
#define MROWS     32          // rows per block in layer kernel
#define ASTRIDE   264         // LDS row stride in shorts (16B-aligned, breaks pow2)
#define NB_SCAN   196         // ceil(N_NODES/256)

typedef short  short8 __attribute__((ext_vector_type(8)));
typedef short  short4_t __attribute__((ext_vector_type(4)));
typedef float  f32x4  __attribute__((ext_vector_type(4)));

__device__ __forceinline__ void split_bf16(float v, short& hi, short& lo) {
    unsigned u  = __float_as_uint(v);
    unsigned hb = u & 0xFFFF0000u;
    hi = (short)(u >> 16);
    float rem = v - __uint_as_float(hb);
    lo = (short)(__float_as_uint(rem) >> 16);
}

__device__ __forceinline__ void split4(float x, float y, float z, float w,
                                       short4_t& hi, short4_t& lo) {
    short h, l;
    split_bf16(x, h, l); hi[0] = h; lo[0] = l;
    split_bf16(y, h, l); hi[1] = h; lo[1] = l;
    split_bf16(z, h, l); hi[2] = h; lo[2] = l;
    split_bf16(w, h, l); hi[3] = h; lo[3] = l;
}

// ---------------------------------------------------------------------------
__global__ void deg_int_kernel(const int* __restrict__ dst, int* __restrict__ deg) {
    int e = blockIdx.x * blockDim.x + threadIdx.x;
    if (e < N_EDGES) atomicAdd(&deg[dst[e]], 1);
}

// batch is sorted -> per-graph count via two binary searches, no atomics
__global__ __launch_bounds__(256) void cnt_bs_kernel(const int* __restrict__ batch,
                                                     float* __restrict__ inv_cnt) {
    int g = blockIdx.x * 256 + threadIdx.x;
    if (g >= N_GRAPHS) return;
    int lo = 0, hi = N_NODES;
    while (lo < hi) { int mid = (lo + hi) >> 1; if (batch[mid] < g) lo = mid + 1; else hi = mid; }
    int start = lo;
    lo = start; hi = N_NODES;
    while (lo < hi) { int mid = (lo + hi) >> 1; if (batch[mid] < g + 1) lo = mid + 1; else hi = mid; }
    int c = lo - start;
    inv_cnt[g] = 1.0f / fmaxf((float)c, 1.0f);
}

// ---- parallel scan: phase 1 — per-block sums of deg ----
__global__ __launch_bounds__(256) void bsum_kernel(const int* __restrict__ deg,
                                                   int* __restrict__ bsum) {
    int i = blockIdx.x * 256 + threadIdx.x;
    int v = (i < N_NODES) ? deg[i] : 0;
    #pragma unroll
    for (int off = 32; off > 0; off >>= 1) v += __shfl_down(v, off, 64);
    __shared__ int wsum[4];
    int lane = threadIdx.x & 63, w = threadIdx.x >> 6;
    if (lane == 0) wsum[w] = v;
    __syncthreads();
    if (threadIdx.x == 0) bsum[blockIdx.x] = wsum[0] + wsum[1] + wsum[2] + wsum[3];
}

// ---- phase 2 — single-block exclusive scan of the 196 block sums ----
__global__ __launch_bounds__(256) void bscan_kernel(int* __restrict__ bsum) {
    __shared__ int s[256];
    int t = threadIdx.x;
    int v = (t < NB_SCAN) ? bsum[t] : 0;
    s[t] = v;
    __syncthreads();
    for (int off = 1; off < 256; off <<= 1) {
        int x = s[t];
        int add = (t >= off) ? s[t - off] : 0;
        __syncthreads();
        s[t] = x + add;
        __syncthreads();
    }
    bsum[t] = (t == 0) ? 0 : s[t - 1];   // exclusive
}

// ---- phase 3 — per-block scan + apply ----
__global__ __launch_bounds__(256) void scan_apply_kernel(
    const int* __restrict__ deg, const int* __restrict__ boff,
    int* __restrict__ row_start, int* __restrict__ cursor,
    float* __restrict__ inv_deg)
{
    __shared__ int s[256];
    int b = blockIdx.x, t = threadIdx.x;
    int i = b * 256 + t;
    int d = (i < N_NODES) ? deg[i] : 0;
    s[t] = d;
    __syncthreads();
    for (int off = 1; off < 256; off <<= 1) {
        int x = s[t];
        int add = (t >= off) ? s[t - off] : 0;
        __syncthreads();
        s[t] = x + add;
        __syncthreads();
    }
    int excl = s[t] - d + boff[b];
    if (i < N_NODES) {
        row_start[i] = excl;
        cursor[i]    = excl;
        inv_deg[i]   = 1.0f / fmaxf((float)d, 1.0f);
    }
    if (b == 0 && t == 0) row_start[N_NODES] = N_EDGES;
}

__global__ void fill_kernel(const int* __restrict__ src, const int* __restrict__ dst,
                            int* __restrict__ cursor, int* __restrict__ eidx) {
    int e = blockIdx.x * blockDim.x + threadIdx.x;
    if (e < N_EDGES) {
        int p = atomicAdd(&cursor[dst[e]], 1);
        eidx[p] = src[e];
    }
}

// W pre-transpose + split, all 4 layers in one launch.
// gt = l*32768 + n*256 + k  (n<128, k<256)
__global__ __launch_bounds__(256) void wsplit_all_kernel(
    const float* __restrict__ Wl0, const float* __restrict__ Wr0,
    const float* __restrict__ Wl1, const float* __restrict__ Wr1,
    const float* __restrict__ Wl2, const float* __restrict__ Wr2,
    const float* __restrict__ Wl3, const float* __restrict__ Wr3,
    short* __restrict__ wtbase)
{
    int gt = blockIdx.x * 256 + threadIdx.x;
    int l  = gt >> 15;
    int t  = gt & 32767;
    const float* Wl; const float* Wr;
    switch (l) {
        case 0:  Wl = Wl0; Wr = Wr0; break;
        case 1:  Wl = Wl1; Wr = Wr1; break;
        case 2:  Wl = Wl2; Wr = Wr2; break;
        default: Wl = Wl3; Wr = Wr3; break;
    }
    int n = t >> 8, k = t & 255;
    float w = (k < F) ? Wl[k * F + n] : Wr[(k - F) * F + n];
    short h, lo;
    split_bf16(w, h, lo);
    short* hi_plane = wtbase + (size_t)l * 65536;
    hi_plane[t]         = h;
    hi_plane[32768 + t] = lo;
}

// ---------------------------------------------------------------------------
// Fused layer: f32 gather-mean -> split-bf16 MFMA dual-GEMM -> bias+relu.
// block = 512 threads (8 waves), 32 rows. A = [agg | self] : [32 x 256].
// Gather: each lane owns TWO rows (rr, rr+16) concurrently; 4+4 predicated
// edge loads per iteration (no remainder loop) for deep MLP.
__global__ __launch_bounds__(512) void layer_kernel(
    const float* __restrict__ h_in, const int* __restrict__ row_start,
    const int* __restrict__ eidx, const float* __restrict__ inv_deg,
    const short* __restrict__ wt_hi, const short* __restrict__ wt_lo,
    const float* __restrict__ b, float* __restrict__ h_out)
{
    __shared__ short Ahi[MROWS][ASTRIDE];
    __shared__ short Alo[MROWS][ASTRIDE];

    const int t    = threadIdx.x;
    const int base = blockIdx.x * MROWS;

    // ---- gather phase ----
    {
        const int c4   = t & 31;
        const int rr   = t >> 5;            // 0..15
        const int rowA = base + rr;          // always < N_NODES (grid sized)
        const int rowB = rowA + 16;
        const bool vB  = (rowB < N_NODES);

        int a0 = row_start[rowA], a1 = row_start[rowA + 1];
        int b0 = 0, b1 = 0;
        if (vB) { b0 = row_start[rowB]; b1 = row_start[rowB + 1]; }
        const int na = a1 - a0, nb = b1 - b0;

        float scA = inv_deg[rowA];
        float scB = vB ? inv_deg[rowB] : 0.0f;

        float4 sA = ((const float4*)(h_in + (size_t)rowA * F))[c4];
        float4 sB = {0, 0, 0, 0};
        if (vB) sB = ((const float4*)(h_in + (size_t)rowB * F))[c4];

        f32x4 aA = {0, 0, 0, 0}, aB = {0, 0, 0, 0};
        const int mx = na > nb ? na : nb;
        for (int eo = 0; eo < mx; eo += 4) {
            int   idxA[4], idxB[4];
            float mA[4], mB[4];
            #pragma unroll
            for (int u = 0; u < 4; ++u) {
                bool okA = (eo + u) < na;
                bool okB = (eo + u) < nb;
                int  slA = okA ? a0 + eo + u : a0;   // a0 <= N_EDGES: eidx[a0] stays inside d_ws
                int  slB = okB ? b0 + eo + u : b0;
                int ia = eidx[slA];
                int ib = eidx[slB];
                idxA[u] = okA ? ia : 0;
                idxB[u] = okB ? ib : 0;
                mA[u] = okA ? 1.0f : 0.0f;
                mB[u] = okB ? 1.0f : 0.0f;
            }
            #pragma unroll
            for (int u = 0; u < 4; ++u) {
                float4 va = ((const float4*)(h_in + (size_t)idxA[u] * F))[c4];
                float4 vb = ((const float4*)(h_in + (size_t)idxB[u] * F))[c4];
                aA[0] = fmaf(va.x, mA[u], aA[0]);
                aA[1] = fmaf(va.y, mA[u], aA[1]);
                aA[2] = fmaf(va.z, mA[u], aA[2]);
                aA[3] = fmaf(va.w, mA[u], aA[3]);
                aB[0] = fmaf(vb.x, mB[u], aB[0]);
                aB[1] = fmaf(vb.y, mB[u], aB[1]);
                aB[2] = fmaf(vb.z, mB[u], aB[2]);
                aB[3] = fmaf(vb.w, mB[u], aB[3]);
            }
        }

        short4_t h4, l4;
        split4(aA[0] * scA, aA[1] * scA, aA[2] * scA, aA[3] * scA, h4, l4);
        *(short4_t*)&Ahi[rr][c4 * 4] = h4;
        *(short4_t*)&Alo[rr][c4 * 4] = l4;
        split4(sA.x, sA.y, sA.z, sA.w, h4, l4);
        *(short4_t*)&Ahi[rr][F + c4 * 4] = h4;
        *(short4_t*)&Alo[rr][F + c4 * 4] = l4;

        split4(aB[0] * scB, aB[1] * scB, aB[2] * scB, aB[3] * scB, h4, l4);
        *(short4_t*)&Ahi[rr + 16][c4 * 4] = h4;
        *(short4_t*)&Alo[rr + 16][c4 * 4] = l4;
        split4(sB.x, sB.y, sB.z, sB.w, h4, l4);
        *(short4_t*)&Ahi[rr + 16][F + c4 * 4] = h4;
        *(short4_t*)&Alo[rr + 16][F + c4 * 4] = l4;
    }
    __syncthreads();

    // ---- MFMA phase: wave w owns cols [w*16, w*16+16) ----
    const int w    = t >> 6;         // 0..7
    const int lane = t & 63;
    const int m    = lane & 15;
    const int quad = lane >> 4;
    const int n0   = w * 16 + m;

    f32x4 acc0 = {0,0,0,0};          // rows 0..15
    f32x4 acc1 = {0,0,0,0};          // rows 16..31

    #pragma unroll
    for (int ks = 0; ks < 8; ++ks) {
        const int ko = ks * 32 + quad * 8;
        short8 ah0 = *(const short8*)&Ahi[m][ko];
        short8 ah1 = *(const short8*)&Ahi[16 + m][ko];
        short8 al0 = *(const short8*)&Alo[m][ko];
        short8 al1 = *(const short8*)&Alo[16 + m][ko];
        short8 bh  = *(const short8*)&wt_hi[(size_t)n0 * 256 + ko];
        short8 bl  = *(const short8*)&wt_lo[(size_t)n0 * 256 + ko];

        acc0 = __builtin_amdgcn_mfma_f32_16x16x32_bf16(ah0, bh, acc0, 0, 0, 0);
        acc0 = __builtin_amdgcn_mfma_f32_16x16x32_bf16(ah0, bl, acc0, 0, 0, 0);
        acc0 = __builtin_amdgcn_mfma_f32_16x16x32_bf16(al0, bh, acc0, 0, 0, 0);

        acc1 = __builtin_amdgcn_mfma_f32_16x16x32_bf16(ah1, bh, acc1, 0, 0, 0);
        acc1 = __builtin_amdgcn_mfma_f32_16x16x32_bf16(ah1, bl, acc1, 0, 0, 0);
        acc1 = __builtin_amdgcn_mfma_f32_16x16x32_bf16(al1, bh, acc1, 0, 0, 0);
    }

    // ---- epilogue: C/D layout col=lane&15 (=n0 col), row=quad*4+reg ----
    float bj = b[n0];
    #pragma unroll
    for (int reg = 0; reg < 4; ++reg) {
        int r0 = base + quad * 4 + reg;
        int r1 = r0 + 16;
        if (r0 < N_NODES) h_out[(size_t)r0 * F + n0] = fmaxf(acc0[reg] + bj, 0.0f);
        if (r1 < N_NODES) h_out[(size_t)r1 * F + n0] = fmaxf(acc1[reg] + bj, 0.0f);
    }
}

// ---------------------------------------------------------------------------
// Segmented pool: batch is sorted; each block walks 128 consecutive nodes,
// accumulating per-column until the graph id changes -> few atomics.
__global__ __launch_bounds__(128) void pool_kernel(
    const int* __restrict__ batch, const float* __restrict__ h,
    float* __restrict__ pooled)
{
    int j  = threadIdx.x;            // col
    int n0 = blockIdx.x * 128;
    int g  = batch[n0];
    float acc = 0.0f;
    #pragma unroll 4
    for (int r = 0; r < 128; ++r) {
        int row = n0 + r;
        if (row >= N_NODES) break;
        int gb = batch[row];
        if (gb != g) {
            atomicAdd(&pooled[(size_t)g * F + j], acc);
            acc = 0.0f;
            g = gb;
        }
        acc += h[(size_t)row * F + j];
    }
    atomicAdd(&pooled[(size_t)g * F + j], acc);
}

__global__ __launch_bounds__(128) void head_kernel(
    const float* __restrict__ pooled, const float* __restrict__ inv_cnt,
    const float* __restrict__ Wf1, const float* __restrict__ bf1,
    const float* __restrict__ Wf2, const float* __restrict__ bf2,
    float* __restrict__ out)
{
    __shared__ float p[F];
    __shared__ float emb[F];
    int g = blockIdx.x;
    int j = threadIdx.x;
    p[j] = pooled[(size_t)g * F + j] * inv_cnt[g];
    __syncthreads();
    float acc = bf1[j];
    #pragma unroll 8
    for (int k = 0; k < F; ++k) acc += p[k] * Wf1[k * F + j];
    emb[j] = acc;
    __syncthreads();
    if (j < 2) {
        float o = bf2[j];
        for (int k = 0; k < F; ++k) o += emb[k] * Wf2[k * 2 + j];
        out[(size_t)g * 2 + j] = o;
    }
}

extern "C" void kernel_launch(void* const* d_in, const int* in_sizes, int n_in,
                              void* d_out, int out_size, void* d_ws, size_t ws_size,
                              hipStream_t stream) {
    const float* x     = (const float*)d_in[0];
    const int*   ei    = (const int*)d_in[1];
    const int*   src   = ei;
    const int*   dst   = ei + N_EDGES;
    const int*   batch = (const int*)d_in[2];
    const float* Wl[4] = {(const float*)d_in[4],  (const float*)d_in[7],
                          (const float*)d_in[10], (const float*)d_in[13]};
    const float* Wr[4] = {(const float*)d_in[5],  (const float*)d_in[8],
                          (const float*)d_in[11], (const float*)d_in[14]};
    const float* bb[4] = {(const float*)d_in[6],  (const float*)d_in[9],
                          (const float*)d_in[12], (const float*)d_in[15]};
    const float* Wf1 = (const float*)d_in[16];
    const float* bf1 = (const float*)d_in[17];
    const float* Wf2 = (const float*)d_in[18];
    const float* bf2 = (const float*)d_in[19];
    float* out = (float*)d_out;

    // workspace layout
    float* ws = (float*)d_ws;
    const size_t HSZ = (size_t)N_NODES * F;
    float* B0        = ws;
    float* B1        = B0 + HSZ;
    float* inv_deg   = B1 + HSZ;                        // N_NODES
    float* inv_cnt   = inv_deg + N_NODES;               // N_GRAPHS
    int*   row_start = (int*)(inv_cnt + N_GRAPHS);      // N_NODES+1
    int*   cursor    = row_start + N_NODES + 1;         // N_NODES
    int*   eidx      = cursor + N_NODES;                // N_EDGES
    // zero region: deg_i + pooled, contiguous (one memset)
    int*   deg_i     = eidx + N_EDGES;                  // N_NODES
    float* pooled    = (float*)(deg_i + N_NODES);       // N_GRAPHS*F
    int*   bsum      = (int*)(pooled + (size_t)N_GRAPHS * F);  // 256
    short* wtbase    = (short*)(bsum + 256);            // 4 x 65536 shorts

    (void)hipMemsetAsync(deg_i, 0,
        (N_NODES + (size_t)N_GRAPHS * F) * sizeof(int), stream);

    // CSR build
    deg_int_kernel<<<(N_EDGES + 255) / 256, 256, 0, stream>>>(dst, deg_i);
    bsum_kernel<<<NB_SCAN, 256, 0, stream>>>(deg_i, bsum);
    bscan_kernel<<<1, 256, 0, stream>>>(bsum);
    scan_apply_kernel<<<NB_SCAN, 256, 0, stream>>>(deg_i, bsum, row_start, cursor, inv_deg);
    fill_kernel<<<(N_EDGES + 255) / 256, 256, 0, stream>>>(src, dst, cursor, eidx);

    cnt_bs_kernel<<<2, 256, 0, stream>>>(batch, inv_cnt);

    // W transpose+split (all layers, one launch)
    wsplit_all_kernel<<<512, 256, 0, stream>>>(
        Wl[0], Wr[0], Wl[1], Wr[1], Wl[2], Wr[2], Wl[3], Wr[3], wtbase);

    const int layer_blocks = (N_NODES + MROWS - 1) / MROWS;  // 1563
    const float* hin = x;
    float* buf[2] = {B0, B1};
    for (int l = 0; l < 4; ++l) {
        float* tgt = buf[l & 1];
        const short* whi = wtbase + (size_t)l * 65536;
        const short* wlo = whi + 32768;
        layer_kernel<<<layer_blocks, 512, 0, stream>>>(
            hin, row_start, eidx, inv_deg, whi, wlo, bb[l], tgt);
        hin = tgt;
    }

    const int pool_blocks = (N_NODES + 127) / 128;
    pool_kernel<<<pool_blocks, 128, 0, stream>>>(batch, hin, pooled);
    head_kernel<<<N_GRAPHS, 128, 0, stream>>>(pooled, inv_cnt, Wf1, bf1, Wf2, bf2, out);
}

// Round 7
// 469.815 us; speedup vs baseline: 10.9269x; 1.0735x over previous
//
#include <hip/hip_runtime.h>

#define N_NODES   50000
#define N_EDGES   600000
#define F         128
#define N_GRAPHS  512
#define MROWS     32          // rows per block in layer kernel
#define ASTRIDE   264         // LDS row stride in shorts (16B-aligned, breaks pow2)
#define NB_SCAN   196         // ceil(N_NODES/256)
#define ECAP      1536        // LDS edge-index staging capacity per block

typedef short  short8 __attribute__((ext_vector_type(8)));
typedef short  short4_t __attribute__((ext_vector_type(4)));
typedef float  f32x4  __attribute__((ext_vector_type(4)));

__device__ __forceinline__ void split_bf16(float v, short& hi, short& lo) {
    unsigned u  = __float_as_uint(v);
    unsigned hb = u & 0xFFFF0000u;
    hi = (short)(u >> 16);
    float rem = v - __uint_as_float(hb);
    lo = (short)(__float_as_uint(rem) >> 16);
}

__device__ __forceinline__ void split4(float x, float y, float z, float w,
                                       short4_t& hi, short4_t& lo) {
    short h, l;
    split_bf16(x, h, l); hi[0] = h; lo[0] = l;
    split_bf16(y, h, l); hi[1] = h; lo[1] = l;
    split_bf16(z, h, l); hi[2] = h; lo[2] = l;
    split_bf16(w, h, l); hi[3] = h; lo[3] = l;
}

// ---------------------------------------------------------------------------
__global__ void deg_int_kernel(const int* __restrict__ dst, int* __restrict__ deg) {
    int e = blockIdx.x * blockDim.x + threadIdx.x;
    if (e < N_EDGES) atomicAdd(&deg[dst[e]], 1);
}

// ---- parallel scan: phase 1 — per-block sums of deg ----
__global__ __launch_bounds__(256) void bsum_kernel(const int* __restrict__ deg,
                                                   int* __restrict__ bsum) {
    int i = blockIdx.x * 256 + threadIdx.x;
    int v = (i < N_NODES) ? deg[i] : 0;
    #pragma unroll
    for (int off = 32; off > 0; off >>= 1) v += __shfl_down(v, off, 64);
    __shared__ int wsum[4];
    int lane = threadIdx.x & 63, w = threadIdx.x >> 6;
    if (lane == 0) wsum[w] = v;
    __syncthreads();
    if (threadIdx.x == 0) bsum[blockIdx.x] = wsum[0] + wsum[1] + wsum[2] + wsum[3];
}

// ---- merged phase 2: block 0 = exclusive scan of 196 block sums;
//      blocks 1..512 = W transpose+split for all 4 layers ----
__global__ __launch_bounds__(256) void p2_kernel(
    int* __restrict__ bsum,
    const float* __restrict__ Wl0, const float* __restrict__ Wr0,
    const float* __restrict__ Wl1, const float* __restrict__ Wr1,
    const float* __restrict__ Wl2, const float* __restrict__ Wr2,
    const float* __restrict__ Wl3, const float* __restrict__ Wr3,
    short* __restrict__ wtbase)
{
    if (blockIdx.x == 0) {
        __shared__ int s[256];
        int t = threadIdx.x;
        int v = (t < NB_SCAN) ? bsum[t] : 0;
        s[t] = v;
        __syncthreads();
        for (int off = 1; off < 256; off <<= 1) {
            int x = s[t];
            int add = (t >= off) ? s[t - off] : 0;
            __syncthreads();
            s[t] = x + add;
            __syncthreads();
        }
        bsum[t] = (t == 0) ? 0 : s[t - 1];   // exclusive
    } else {
        int gt = (blockIdx.x - 1) * 256 + threadIdx.x;   // 0 .. 131071
        int l  = gt >> 15;
        int t  = gt & 32767;
        const float* Wl; const float* Wr;
        switch (l) {
            case 0:  Wl = Wl0; Wr = Wr0; break;
            case 1:  Wl = Wl1; Wr = Wr1; break;
            case 2:  Wl = Wl2; Wr = Wr2; break;
            default: Wl = Wl3; Wr = Wr3; break;
        }
        int n = t >> 8, k = t & 255;
        float w = (k < F) ? Wl[k * F + n] : Wr[(k - F) * F + n];
        short h, lo;
        split_bf16(w, h, lo);
        short* hi_plane = wtbase + (size_t)l * 65536;
        hi_plane[t]         = h;
        hi_plane[32768 + t] = lo;
    }
}

// ---- phase 3 — per-block scan + apply ----
__global__ __launch_bounds__(256) void scan_apply_kernel(
    const int* __restrict__ deg, const int* __restrict__ boff,
    int* __restrict__ row_start, int* __restrict__ cursor,
    float* __restrict__ inv_deg)
{
    __shared__ int s[256];
    int b = blockIdx.x, t = threadIdx.x;
    int i = b * 256 + t;
    int d = (i < N_NODES) ? deg[i] : 0;
    s[t] = d;
    __syncthreads();
    for (int off = 1; off < 256; off <<= 1) {
        int x = s[t];
        int add = (t >= off) ? s[t - off] : 0;
        __syncthreads();
        s[t] = x + add;
        __syncthreads();
    }
    int excl = s[t] - d + boff[b];
    if (i < N_NODES) {
        row_start[i] = excl;
        cursor[i]    = excl;
        inv_deg[i]   = 1.0f / fmaxf((float)d, 1.0f);
    }
    if (b == 0 && t == 0) row_start[N_NODES] = N_EDGES;
}

__global__ void fill_kernel(const int* __restrict__ src, const int* __restrict__ dst,
                            int* __restrict__ cursor, int* __restrict__ eidx) {
    int e = blockIdx.x * blockDim.x + threadIdx.x;
    if (e < N_EDGES) {
        int p = atomicAdd(&cursor[dst[e]], 1);
        eidx[p] = src[e];
    }
}

// ---------------------------------------------------------------------------
// Fused layer: f32 gather-mean -> split-bf16 MFMA dual-GEMM -> bias+relu.
// block = 512 threads (8 waves), 32 rows. A = [agg | self] : [32 x 256].
// Block's contiguous edge-index window staged in LDS.
__global__ __launch_bounds__(512) void layer_kernel(
    const float* __restrict__ h_in, const int* __restrict__ row_start,
    const int* __restrict__ eidx, const float* __restrict__ inv_deg,
    const short* __restrict__ wt_hi, const short* __restrict__ wt_lo,
    const float* __restrict__ b, float* __restrict__ h_out)
{
    __shared__ short Ahi[MROWS][ASTRIDE];
    __shared__ short Alo[MROWS][ASTRIDE];
    __shared__ int   eshare[ECAP];

    const int t    = threadIdx.x;
    const int base = blockIdx.x * MROWS;

    // ---- stage edge window ----
    const int blk_end = (base + MROWS < N_NODES) ? base + MROWS : N_NODES;
    const int s_blk0  = row_start[base];
    const int s_blk1  = row_start[blk_end];
    const int ecnt    = s_blk1 - s_blk0;
    const bool use_lds = (ecnt <= ECAP);
    if (use_lds) {
        for (int i = t; i < ecnt; i += 512) eshare[i] = eidx[s_blk0 + i];
    }
    __syncthreads();

    // ---- gather phase ----
    {
        const int c4   = t & 31;
        const int rr   = t >> 5;            // 0..15
        const int rowA = base + rr;          // always < N_NODES (grid sized)
        const int rowB = rowA + 16;
        const bool vB  = (rowB < N_NODES);

        int a0 = row_start[rowA] - s_blk0, a1 = row_start[rowA + 1] - s_blk0;
        int b0 = 0, b1 = 0;
        if (vB) { b0 = row_start[rowB] - s_blk0; b1 = row_start[rowB + 1] - s_blk0; }
        const int na = a1 - a0, nb = b1 - b0;

        float scA = inv_deg[rowA];
        float scB = vB ? inv_deg[rowB] : 0.0f;

        float4 sA = ((const float4*)(h_in + (size_t)rowA * F))[c4];
        float4 sB = {0, 0, 0, 0};
        if (vB) sB = ((const float4*)(h_in + (size_t)rowB * F))[c4];

        f32x4 aA = {0, 0, 0, 0}, aB = {0, 0, 0, 0};
        const int mx = na > nb ? na : nb;
        for (int eo = 0; eo < mx; eo += 4) {
            int   idxA[4], idxB[4];
            float mA[4], mB[4];
            #pragma unroll
            for (int u = 0; u < 4; ++u) {
                bool okA = (eo + u) < na;
                bool okB = (eo + u) < nb;
                int offA = okA ? a0 + eo + u : 0;
                int offB = okB ? b0 + eo + u : 0;
                int ia = use_lds ? eshare[offA] : eidx[s_blk0 + offA];
                int ib = use_lds ? eshare[offB] : eidx[s_blk0 + offB];
                idxA[u] = okA ? ia : 0;
                idxB[u] = okB ? ib : 0;
                mA[u] = okA ? 1.0f : 0.0f;
                mB[u] = okB ? 1.0f : 0.0f;
            }
            #pragma unroll
            for (int u = 0; u < 4; ++u) {
                float4 va = ((const float4*)(h_in + (size_t)idxA[u] * F))[c4];
                float4 vb = ((const float4*)(h_in + (size_t)idxB[u] * F))[c4];
                aA[0] = fmaf(va.x, mA[u], aA[0]);
                aA[1] = fmaf(va.y, mA[u], aA[1]);
                aA[2] = fmaf(va.z, mA[u], aA[2]);
                aA[3] = fmaf(va.w, mA[u], aA[3]);
                aB[0] = fmaf(vb.x, mB[u], aB[0]);
                aB[1] = fmaf(vb.y, mB[u], aB[1]);
                aB[2] = fmaf(vb.z, mB[u], aB[2]);
                aB[3] = fmaf(vb.w, mB[u], aB[3]);
            }
        }

        short4_t h4, l4;
        split4(aA[0] * scA, aA[1] * scA, aA[2] * scA, aA[3] * scA, h4, l4);
        *(short4_t*)&Ahi[rr][c4 * 4] = h4;
        *(short4_t*)&Alo[rr][c4 * 4] = l4;
        split4(sA.x, sA.y, sA.z, sA.w, h4, l4);
        *(short4_t*)&Ahi[rr][F + c4 * 4] = h4;
        *(short4_t*)&Alo[rr][F + c4 * 4] = l4;

        split4(aB[0] * scB, aB[1] * scB, aB[2] * scB, aB[3] * scB, h4, l4);
        *(short4_t*)&Ahi[rr + 16][c4 * 4] = h4;
        *(short4_t*)&Alo[rr + 16][c4 * 4] = l4;
        split4(sB.x, sB.y, sB.z, sB.w, h4, l4);
        *(short4_t*)&Ahi[rr + 16][F + c4 * 4] = h4;
        *(short4_t*)&Alo[rr + 16][F + c4 * 4] = l4;
    }
    __syncthreads();

    // ---- MFMA phase: wave w owns cols [w*16, w*16+16) ----
    const int w    = t >> 6;         // 0..7
    const int lane = t & 63;
    const int m    = lane & 15;
    const int quad = lane >> 4;
    const int n0   = w * 16 + m;

    f32x4 acc0 = {0,0,0,0};          // rows 0..15
    f32x4 acc1 = {0,0,0,0};          // rows 16..31

    #pragma unroll
    for (int ks = 0; ks < 8; ++ks) {
        const int ko = ks * 32 + quad * 8;
        short8 ah0 = *(const short8*)&Ahi[m][ko];
        short8 ah1 = *(const short8*)&Ahi[16 + m][ko];
        short8 al0 = *(const short8*)&Alo[m][ko];
        short8 al1 = *(const short8*)&Alo[16 + m][ko];
        short8 bh  = *(const short8*)&wt_hi[(size_t)n0 * 256 + ko];
        short8 bl  = *(const short8*)&wt_lo[(size_t)n0 * 256 + ko];

        acc0 = __builtin_amdgcn_mfma_f32_16x16x32_bf16(ah0, bh, acc0, 0, 0, 0);
        acc0 = __builtin_amdgcn_mfma_f32_16x16x32_bf16(ah0, bl, acc0, 0, 0, 0);
        acc0 = __builtin_amdgcn_mfma_f32_16x16x32_bf16(al0, bh, acc0, 0, 0, 0);

        acc1 = __builtin_amdgcn_mfma_f32_16x16x32_bf16(ah1, bh, acc1, 0, 0, 0);
        acc1 = __builtin_amdgcn_mfma_f32_16x16x32_bf16(ah1, bl, acc1, 0, 0, 0);
        acc1 = __builtin_amdgcn_mfma_f32_16x16x32_bf16(al1, bh, acc1, 0, 0, 0);
    }

    // ---- epilogue: C/D layout col=lane&15 (=n0 col), row=quad*4+reg ----
    float bj = b[n0];
    #pragma unroll
    for (int reg = 0; reg < 4; ++reg) {
        int r0 = base + quad * 4 + reg;
        int r1 = r0 + 16;
        if (r0 < N_NODES) h_out[(size_t)r0 * F + n0] = fmaxf(acc0[reg] + bj, 0.0f);
        if (r1 < N_NODES) h_out[(size_t)r1 * F + n0] = fmaxf(acc1[reg] + bj, 0.0f);
    }
}

// ---------------------------------------------------------------------------
// Fused pool + head: block g owns graph g (batch sorted -> binary search
// node range). mean-pool in registers, 128->128 and 128->2 MLP via LDS.
__global__ __launch_bounds__(128) void poolhead_kernel(
    const int* __restrict__ batch, const float* __restrict__ h,
    const float* __restrict__ Wf1, const float* __restrict__ bf1,
    const float* __restrict__ Wf2, const float* __restrict__ bf2,
    float* __restrict__ out)
{
    int g = blockIdx.x;
    int j = threadIdx.x;
    int lo = 0, hi = N_NODES;
    while (lo < hi) { int m = (lo + hi) >> 1; if (batch[m] < g) lo = m + 1; else hi = m; }
    int start = lo;
    hi = N_NODES;
    while (lo < hi) { int m = (lo + hi) >> 1; if (batch[m] <= g) lo = m + 1; else hi = m; }
    int end = lo;

    float acc = 0.0f;
    int r = start;
    for (; r + 4 <= end; r += 4) {
        float v0 = h[(size_t)(r + 0) * F + j];
        float v1 = h[(size_t)(r + 1) * F + j];
        float v2 = h[(size_t)(r + 2) * F + j];
        float v3 = h[(size_t)(r + 3) * F + j];
        acc += (v0 + v1) + (v2 + v3);
    }
    for (; r < end; ++r) acc += h[(size_t)r * F + j];

    __shared__ float p[F];
    __shared__ float emb[F];
    p[j] = acc / fmaxf((float)(end - start), 1.0f);
    __syncthreads();
    float e = bf1[j];
    #pragma unroll 8
    for (int k = 0; k < F; ++k) e += p[k] * Wf1[k * F + j];
    emb[j] = e;
    __syncthreads();
    if (j < 2) {
        float o = bf2[j];
        for (int k = 0; k < F; ++k) o += emb[k] * Wf2[k * 2 + j];
        out[(size_t)g * 2 + j] = o;
    }
}

extern "C" void kernel_launch(void* const* d_in, const int* in_sizes, int n_in,
                              void* d_out, int out_size, void* d_ws, size_t ws_size,
                              hipStream_t stream) {
    const float* x     = (const float*)d_in[0];
    const int*   ei    = (const int*)d_in[1];
    const int*   src   = ei;
    const int*   dst   = ei + N_EDGES;
    const int*   batch = (const int*)d_in[2];
    const float* Wl[4] = {(const float*)d_in[4],  (const float*)d_in[7],
                          (const float*)d_in[10], (const float*)d_in[13]};
    const float* Wr[4] = {(const float*)d_in[5],  (const float*)d_in[8],
                          (const float*)d_in[11], (const float*)d_in[14]};
    const float* bb[4] = {(const float*)d_in[6],  (const float*)d_in[9],
                          (const float*)d_in[12], (const float*)d_in[15]};
    const float* Wf1 = (const float*)d_in[16];
    const float* bf1 = (const float*)d_in[17];
    const float* Wf2 = (const float*)d_in[18];
    const float* bf2 = (const float*)d_in[19];
    float* out = (float*)d_out;

    // workspace layout
    float* ws = (float*)d_ws;
    const size_t HSZ = (size_t)N_NODES * F;
    float* B0        = ws;
    float* B1        = B0 + HSZ;
    float* inv_deg   = B1 + HSZ;                        // N_NODES
    int*   row_start = (int*)(inv_deg + N_NODES);       // N_NODES+1
    int*   cursor    = row_start + N_NODES + 1;         // N_NODES
    int*   eidx      = cursor + N_NODES;                // N_EDGES
    int*   deg_i     = eidx + N_EDGES;                  // N_NODES (zeroed)
    int*   bsum      = deg_i + N_NODES;                 // 256
    short* wtbase    = (short*)(bsum + 256);            // 4 x 65536 shorts

    (void)hipMemsetAsync(deg_i, 0, N_NODES * sizeof(int), stream);

    // CSR build + weight prep
    deg_int_kernel<<<(N_EDGES + 255) / 256, 256, 0, stream>>>(dst, deg_i);
    bsum_kernel<<<NB_SCAN, 256, 0, stream>>>(deg_i, bsum);
    p2_kernel<<<513, 256, 0, stream>>>(bsum,
        Wl[0], Wr[0], Wl[1], Wr[1], Wl[2], Wr[2], Wl[3], Wr[3], wtbase);
    scan_apply_kernel<<<NB_SCAN, 256, 0, stream>>>(deg_i, bsum, row_start, cursor, inv_deg);
    fill_kernel<<<(N_EDGES + 255) / 256, 256, 0, stream>>>(src, dst, cursor, eidx);

    const int layer_blocks = (N_NODES + MROWS - 1) / MROWS;  // 1563
    const float* hin = x;
    float* buf[2] = {B0, B1};
    for (int l = 0; l < 4; ++l) {
        float* tgt = buf[l & 1];
        const short* whi = wtbase + (size_t)l * 65536;
        const short* wlo = whi + 32768;
        layer_kernel<<<layer_blocks, 512, 0, stream>>>(
            hin, row_start, eidx, inv_deg, whi, wlo, bb[l], tgt);
        hin = tgt;
    }

    poolhead_kernel<<<N_GRAPHS, 128, 0, stream>>>(batch, hin, Wf1, bf1, Wf2, bf2, out);
}

// Round 8
// 409.106 us; speedup vs baseline: 12.5484x; 1.1484x over previous
//
#include <hip/hip_runtime.h>

#define N_NODES   50000
#define N_EDGES   600000
#define F         128
#define N_GRAPHS  512
#define MROWS     32          // rows per block in layer kernel
#define ASTRIDE   264         // LDS row stride in shorts (16B-aligned, breaks pow2)
#define NB_SCAN   196         // ceil(N_NODES/256)

typedef short          short8   __attribute__((ext_vector_type(8)));
typedef short          short4_t __attribute__((ext_vector_type(4)));
typedef float          f32x4    __attribute__((ext_vector_type(4)));
typedef unsigned int   uint4_t  __attribute__((ext_vector_type(4)));

__device__ __forceinline__ void split_bf16(float v, short& hi, short& lo) {
    unsigned u  = __float_as_uint(v);
    unsigned hb = u & 0xFFFF0000u;
    hi = (short)(u >> 16);
    float rem = v - __uint_as_float(hb);
    lo = (short)(__float_as_uint(rem) >> 16);
}

// f32 -> bf16 round-to-nearest-even
__device__ __forceinline__ unsigned short f2bf_rne(float f) {
    unsigned u = __float_as_uint(f);
    u += 0x7FFFu + ((u >> 16) & 1u);
    return (unsigned short)(u >> 16);
}

// ---------------------------------------------------------------------------
__global__ void deg_int_kernel(const int* __restrict__ dst, int* __restrict__ deg) {
    int e = blockIdx.x * blockDim.x + threadIdx.x;
    if (e < N_EDGES) atomicAdd(&deg[dst[e]], 1);
}

// x (f32) -> xb (bf16), 8 elems/thread
__global__ __launch_bounds__(256) void x2bf_kernel(const float* __restrict__ x,
                                                   unsigned short* __restrict__ xb) {
    int i = blockIdx.x * 256 + threadIdx.x;          // i < N_NODES*F/8
    if (i >= (N_NODES * F) / 8) return;
    float4 a = ((const float4*)x)[2 * i];
    float4 b = ((const float4*)x)[2 * i + 1];
    short8 o;
    o[0] = (short)f2bf_rne(a.x); o[1] = (short)f2bf_rne(a.y);
    o[2] = (short)f2bf_rne(a.z); o[3] = (short)f2bf_rne(a.w);
    o[4] = (short)f2bf_rne(b.x); o[5] = (short)f2bf_rne(b.y);
    o[6] = (short)f2bf_rne(b.z); o[7] = (short)f2bf_rne(b.w);
    ((short8*)xb)[i] = o;
}

// ---- parallel scan: phase 1 — per-block sums of deg ----
__global__ __launch_bounds__(256) void bsum_kernel(const int* __restrict__ deg,
                                                   int* __restrict__ bsum) {
    int i = blockIdx.x * 256 + threadIdx.x;
    int v = (i < N_NODES) ? deg[i] : 0;
    #pragma unroll
    for (int off = 32; off > 0; off >>= 1) v += __shfl_down(v, off, 64);
    __shared__ int wsum[4];
    int lane = threadIdx.x & 63, w = threadIdx.x >> 6;
    if (lane == 0) wsum[w] = v;
    __syncthreads();
    if (threadIdx.x == 0) bsum[blockIdx.x] = wsum[0] + wsum[1] + wsum[2] + wsum[3];
}

// ---- merged phase 2: block 0 = scan of block sums; blocks 1..512 = W split ----
__global__ __launch_bounds__(256) void p2_kernel(
    int* __restrict__ bsum,
    const float* __restrict__ Wl0, const float* __restrict__ Wr0,
    const float* __restrict__ Wl1, const float* __restrict__ Wr1,
    const float* __restrict__ Wl2, const float* __restrict__ Wr2,
    const float* __restrict__ Wl3, const float* __restrict__ Wr3,
    short* __restrict__ wtbase)
{
    if (blockIdx.x == 0) {
        __shared__ int s[256];
        int t = threadIdx.x;
        int v = (t < NB_SCAN) ? bsum[t] : 0;
        s[t] = v;
        __syncthreads();
        for (int off = 1; off < 256; off <<= 1) {
            int x = s[t];
            int add = (t >= off) ? s[t - off] : 0;
            __syncthreads();
            s[t] = x + add;
            __syncthreads();
        }
        bsum[t] = (t == 0) ? 0 : s[t - 1];   // exclusive
    } else {
        int gt = (blockIdx.x - 1) * 256 + threadIdx.x;   // 0 .. 131071
        int l  = gt >> 15;
        int t  = gt & 32767;
        const float* Wl; const float* Wr;
        switch (l) {
            case 0:  Wl = Wl0; Wr = Wr0; break;
            case 1:  Wl = Wl1; Wr = Wr1; break;
            case 2:  Wl = Wl2; Wr = Wr2; break;
            default: Wl = Wl3; Wr = Wr3; break;
        }
        int n = t >> 8, k = t & 255;
        float w = (k < F) ? Wl[k * F + n] : Wr[(k - F) * F + n];
        short h, lo;
        split_bf16(w, h, lo);
        short* hi_plane = wtbase + (size_t)l * 65536;
        hi_plane[t]         = h;
        hi_plane[32768 + t] = lo;
    }
}

// ---- phase 3 — per-block scan + apply ----
__global__ __launch_bounds__(256) void scan_apply_kernel(
    const int* __restrict__ deg, const int* __restrict__ boff,
    int* __restrict__ row_start, int* __restrict__ cursor,
    float* __restrict__ inv_deg)
{
    __shared__ int s[256];
    int b = blockIdx.x, t = threadIdx.x;
    int i = b * 256 + t;
    int d = (i < N_NODES) ? deg[i] : 0;
    s[t] = d;
    __syncthreads();
    for (int off = 1; off < 256; off <<= 1) {
        int x = s[t];
        int add = (t >= off) ? s[t - off] : 0;
        __syncthreads();
        s[t] = x + add;
        __syncthreads();
    }
    int excl = s[t] - d + boff[b];
    if (i < N_NODES) {
        row_start[i] = excl;
        cursor[i]    = excl;
        inv_deg[i]   = 1.0f / fmaxf((float)d, 1.0f);
    }
    if (b == 0 && t == 0) row_start[N_NODES] = N_EDGES;
}

__global__ void fill_kernel(const int* __restrict__ src, const int* __restrict__ dst,
                            int* __restrict__ cursor, int* __restrict__ eidx) {
    int e = blockIdx.x * blockDim.x + threadIdx.x;
    if (e < N_EDGES) {
        int p = atomicAdd(&cursor[dst[e]], 1);
        eidx[p] = src[e];
    }
}

// ---------------------------------------------------------------------------
// Fused layer (bf16 h): gather-mean over bf16 rows (f32 accum) -> split-bf16
// MFMA dual-GEMM -> bias + relu -> bf16 out.
// block = 512 threads (8 waves), 32 rows. A = [agg | self] : [32 x 256].
__global__ __launch_bounds__(512) void layer_kernel(
    const unsigned short* __restrict__ hb_in, const int* __restrict__ row_start,
    const int* __restrict__ eidx, const float* __restrict__ inv_deg,
    const short* __restrict__ wt_hi, const short* __restrict__ wt_lo,
    const float* __restrict__ b, unsigned short* __restrict__ hb_out)
{
    __shared__ short Ahi[MROWS][ASTRIDE];
    __shared__ short Alo[MROWS][ASTRIDE];

    const int t    = threadIdx.x;
    const int base = blockIdx.x * MROWS;

    // ---- gather phase: thread = (row rr, 8-col group c8) ----
    {
        const int c8  = t & 15;          // cols c8*8 .. c8*8+7
        const int rr  = t >> 4;          // 0..31
        const int row = base + rr;
        const bool v  = (row < N_NODES);

        int a0 = 0, na = 0;
        float sc = 0.0f;
        if (v) {
            a0 = row_start[row];
            na = row_start[row + 1] - a0;
            sc = inv_deg[row];
        }

        // self row: bf16-exact
        short8 selfv = {0,0,0,0,0,0,0,0};
        if (v) selfv = *(const short8*)(hb_in + (size_t)row * F + c8 * 8);

        float acc[8] = {0,0,0,0,0,0,0,0};
        for (int eo = 0; eo < na; eo += 8) {
            int   idx[8];
            float msk[8];
            #pragma unroll
            for (int u = 0; u < 8; ++u) {
                bool ok = (eo + u) < na;
                int  sl = ok ? a0 + eo + u : a0;
                int  ia = eidx[sl];
                idx[u] = ok ? ia : 0;
                msk[u] = ok ? 1.0f : 0.0f;
            }
            #pragma unroll
            for (int u = 0; u < 8; ++u) {
                short8 hv = *(const short8*)(hb_in + (size_t)idx[u] * F + c8 * 8);
                uint4_t uw = *(const uint4_t*)&hv;
                #pragma unroll
                for (int q = 0; q < 4; ++q) {
                    unsigned wq = uw[q];
                    float flo = __uint_as_float(wq << 16);
                    float fhi = __uint_as_float(wq & 0xFFFF0000u);
                    acc[2 * q]     = fmaf(flo, msk[u], acc[2 * q]);
                    acc[2 * q + 1] = fmaf(fhi, msk[u], acc[2 * q + 1]);
                }
            }
        }

        // agg half: split f32 mean into hi/lo bf16 planes
        short8 h8, l8;
        #pragma unroll
        for (int k = 0; k < 8; ++k) {
            short h, l;
            split_bf16(acc[k] * sc, h, l);
            h8[k] = h; l8[k] = l;
        }
        *(short8*)&Ahi[rr][c8 * 8] = h8;
        *(short8*)&Alo[rr][c8 * 8] = l8;

        // self half: bf16-exact, lo = 0
        short8 z8 = {0,0,0,0,0,0,0,0};
        *(short8*)&Ahi[rr][F + c8 * 8] = selfv;
        *(short8*)&Alo[rr][F + c8 * 8] = z8;
    }
    __syncthreads();

    // ---- MFMA phase: wave w owns cols [w*16, w*16+16) ----
    const int w    = t >> 6;         // 0..7
    const int lane = t & 63;
    const int m    = lane & 15;
    const int quad = lane >> 4;
    const int n0   = w * 16 + m;

    f32x4 acc0 = {0,0,0,0};          // rows 0..15
    f32x4 acc1 = {0,0,0,0};          // rows 16..31

    #pragma unroll
    for (int ks = 0; ks < 8; ++ks) {
        const int ko = ks * 32 + quad * 8;
        short8 ah0 = *(const short8*)&Ahi[m][ko];
        short8 ah1 = *(const short8*)&Ahi[16 + m][ko];
        short8 al0 = *(const short8*)&Alo[m][ko];
        short8 al1 = *(const short8*)&Alo[16 + m][ko];
        short8 bh  = *(const short8*)&wt_hi[(size_t)n0 * 256 + ko];
        short8 bl  = *(const short8*)&wt_lo[(size_t)n0 * 256 + ko];

        acc0 = __builtin_amdgcn_mfma_f32_16x16x32_bf16(ah0, bh, acc0, 0, 0, 0);
        acc0 = __builtin_amdgcn_mfma_f32_16x16x32_bf16(ah0, bl, acc0, 0, 0, 0);
        acc0 = __builtin_amdgcn_mfma_f32_16x16x32_bf16(al0, bh, acc0, 0, 0, 0);

        acc1 = __builtin_amdgcn_mfma_f32_16x16x32_bf16(ah1, bh, acc1, 0, 0, 0);
        acc1 = __builtin_amdgcn_mfma_f32_16x16x32_bf16(ah1, bl, acc1, 0, 0, 0);
        acc1 = __builtin_amdgcn_mfma_f32_16x16x32_bf16(al1, bh, acc1, 0, 0, 0);
    }

    // ---- epilogue: C/D layout col=lane&15 (=n0 col), row=quad*4+reg ----
    float bj = b[n0];
    #pragma unroll
    for (int reg = 0; reg < 4; ++reg) {
        int r0 = base + quad * 4 + reg;
        int r1 = r0 + 16;
        if (r0 < N_NODES)
            hb_out[(size_t)r0 * F + n0] = f2bf_rne(fmaxf(acc0[reg] + bj, 0.0f));
        if (r1 < N_NODES)
            hb_out[(size_t)r1 * F + n0] = f2bf_rne(fmaxf(acc1[reg] + bj, 0.0f));
    }
}

// ---------------------------------------------------------------------------
// Fused pool + head (bf16 h): block g owns graph g (batch sorted).
__global__ __launch_bounds__(128) void poolhead_kernel(
    const int* __restrict__ batch, const unsigned short* __restrict__ hb,
    const float* __restrict__ Wf1, const float* __restrict__ bf1,
    const float* __restrict__ Wf2, const float* __restrict__ bf2,
    float* __restrict__ out)
{
    int g = blockIdx.x;
    int j = threadIdx.x;
    int lo = 0, hi = N_NODES;
    while (lo < hi) { int m = (lo + hi) >> 1; if (batch[m] < g) lo = m + 1; else hi = m; }
    int start = lo;
    hi = N_NODES;
    while (lo < hi) { int m = (lo + hi) >> 1; if (batch[m] <= g) lo = m + 1; else hi = m; }
    int end = lo;

    float acc = 0.0f;
    int r = start;
    for (; r + 4 <= end; r += 4) {
        float v0 = __uint_as_float((unsigned)hb[(size_t)(r + 0) * F + j] << 16);
        float v1 = __uint_as_float((unsigned)hb[(size_t)(r + 1) * F + j] << 16);
        float v2 = __uint_as_float((unsigned)hb[(size_t)(r + 2) * F + j] << 16);
        float v3 = __uint_as_float((unsigned)hb[(size_t)(r + 3) * F + j] << 16);
        acc += (v0 + v1) + (v2 + v3);
    }
    for (; r < end; ++r)
        acc += __uint_as_float((unsigned)hb[(size_t)r * F + j] << 16);

    __shared__ float p[F];
    __shared__ float emb[F];
    p[j] = acc / fmaxf((float)(end - start), 1.0f);
    __syncthreads();
    float e = bf1[j];
    #pragma unroll 8
    for (int k = 0; k < F; ++k) e += p[k] * Wf1[k * F + j];
    emb[j] = e;
    __syncthreads();
    if (j < 2) {
        float o = bf2[j];
        for (int k = 0; k < F; ++k) o += emb[k] * Wf2[k * 2 + j];
        out[(size_t)g * 2 + j] = o;
    }
}

extern "C" void kernel_launch(void* const* d_in, const int* in_sizes, int n_in,
                              void* d_out, int out_size, void* d_ws, size_t ws_size,
                              hipStream_t stream) {
    const float* x     = (const float*)d_in[0];
    const int*   ei    = (const int*)d_in[1];
    const int*   src   = ei;
    const int*   dst   = ei + N_EDGES;
    const int*   batch = (const int*)d_in[2];
    const float* Wl[4] = {(const float*)d_in[4],  (const float*)d_in[7],
                          (const float*)d_in[10], (const float*)d_in[13]};
    const float* Wr[4] = {(const float*)d_in[5],  (const float*)d_in[8],
                          (const float*)d_in[11], (const float*)d_in[14]};
    const float* bb[4] = {(const float*)d_in[6],  (const float*)d_in[9],
                          (const float*)d_in[12], (const float*)d_in[15]};
    const float* Wf1 = (const float*)d_in[16];
    const float* bf1 = (const float*)d_in[17];
    const float* Wf2 = (const float*)d_in[18];
    const float* bf2 = (const float*)d_in[19];
    float* out = (float*)d_out;

    // workspace layout
    const size_t HSZ = (size_t)N_NODES * F;            // 6.4M elems
    unsigned short* XB  = (unsigned short*)d_ws;       // bf16 x
    unsigned short* HB0 = XB + HSZ;
    unsigned short* HB1 = HB0 + HSZ;
    float* inv_deg   = (float*)(HB1 + HSZ);            // N_NODES
    int*   row_start = (int*)(inv_deg + N_NODES);      // N_NODES+1
    int*   cursor    = row_start + N_NODES + 1;        // N_NODES
    int*   eidx      = cursor + N_NODES;               // N_EDGES
    int*   deg_i     = eidx + N_EDGES;                 // N_NODES (zeroed)
    int*   bsum      = deg_i + N_NODES;                // 256
    short* wtbase    = (short*)(bsum + 256);           // 4 x 65536 shorts

    (void)hipMemsetAsync(deg_i, 0, N_NODES * sizeof(int), stream);

    // CSR build + weight prep + x conversion
    deg_int_kernel<<<(N_EDGES + 255) / 256, 256, 0, stream>>>(dst, deg_i);
    bsum_kernel<<<NB_SCAN, 256, 0, stream>>>(deg_i, bsum);
    p2_kernel<<<513, 256, 0, stream>>>(bsum,
        Wl[0], Wr[0], Wl[1], Wr[1], Wl[2], Wr[2], Wl[3], Wr[3], wtbase);
    scan_apply_kernel<<<NB_SCAN, 256, 0, stream>>>(deg_i, bsum, row_start, cursor, inv_deg);
    fill_kernel<<<(N_EDGES + 255) / 256, 256, 0, stream>>>(src, dst, cursor, eidx);
    x2bf_kernel<<<(int)((HSZ / 8 + 255) / 256), 256, 0, stream>>>(x, XB);

    const int layer_blocks = (N_NODES + MROWS - 1) / MROWS;  // 1563
    const unsigned short* hin = XB;
    unsigned short* buf[2] = {HB0, HB1};
    for (int l = 0; l < 4; ++l) {
        unsigned short* tgt = buf[l & 1];
        const short* whi = wtbase + (size_t)l * 65536;
        const short* wlo = whi + 32768;
        layer_kernel<<<layer_blocks, 512, 0, stream>>>(
            hin, row_start, eidx, inv_deg, whi, wlo, bb[l], tgt);
        hin = tgt;
    }

    poolhead_kernel<<<N_GRAPHS, 128, 0, stream>>>(batch, hin, Wf1, bf1, Wf2, bf2, out);
}